// Round 1
// baseline (2144.220 us; speedup 1.0000x reference)
//
#include <hip/hip_runtime.h>
#include <stdint.h>

#define DEV static __device__ __forceinline__

typedef __bf16 bf16x8 __attribute__((ext_vector_type(8)));
typedef float f32x4 __attribute__((ext_vector_type(4)));

constexpr int Bc = 2, Sc = 4096, Dc = 2048, Hc = 16, KVHc = 8, HDc = 128;
constexpr int DQKc = 1024, DVc = 2048;
constexpr int Mc = Bc * Sc;       // 8192 rows
constexpr int NCATc = 6144;       // Q(1024) | K(1024) | V(2048) | Graw(2048)
constexpr float EPSc = 1e-6f;

DEV uint16_t f2bf(float f) {
  uint32_t u = __float_as_uint(f);
  u += 0x7FFFu + ((u >> 16) & 1u);   // RNE
  return (uint16_t)(u >> 16);
}
DEV float bf2f(uint16_t h) { return __uint_as_float(((uint32_t)h) << 16); }
DEV float sigmoidf_(float z) { return 1.0f / (1.0f + __expf(-z)); }

DEV void unpack8(uint4 u, float* f) {
  f[0] = __uint_as_float(u.x << 16); f[1] = __uint_as_float(u.x & 0xFFFF0000u);
  f[2] = __uint_as_float(u.y << 16); f[3] = __uint_as_float(u.y & 0xFFFF0000u);
  f[4] = __uint_as_float(u.z << 16); f[5] = __uint_as_float(u.z & 0xFFFF0000u);
  f[6] = __uint_as_float(u.w << 16); f[7] = __uint_as_float(u.w & 0xFFFF0000u);
}

// sum across each 16-lane DPP row via row_ror 1,2,4,8
DEV float red16(float x) {
  x += __int_as_float(__builtin_amdgcn_update_dpp(0, __float_as_int(x), 0x121, 0xF, 0xF, true));
  x += __int_as_float(__builtin_amdgcn_update_dpp(0, __float_as_int(x), 0x122, 0xF, 0xF, true));
  x += __int_as_float(__builtin_amdgcn_update_dpp(0, __float_as_int(x), 0x124, 0xF, 0xF, true));
  x += __int_as_float(__builtin_amdgcn_update_dpp(0, __float_as_int(x), 0x128, 0xF, 0xF, true));
  return x;
}

DEV void gload16(void* lds, const void* g) {
  auto gp = (const __attribute__((address_space(1))) uint32_t*)(uintptr_t)g;
  auto lp = (__attribute__((address_space(3))) uint32_t*)(uint32_t)(uintptr_t)lds;
  __builtin_amdgcn_global_load_lds(gp, lp, 16, 0, 0);
}

// ---------------- f32 -> bf16 cast ----------------
__global__ __launch_bounds__(256) void cast_kernel(const float* __restrict__ src,
                                                   uint16_t* __restrict__ dst, int n4) {
  int i = blockIdx.x * blockDim.x + threadIdx.x;
  int stride = gridDim.x * blockDim.x;
  for (; i < n4; i += stride) {
    float4 v = *(const float4*)(src + (size_t)i * 4);
    ushort4 o;
    o.x = f2bf(v.x); o.y = f2bf(v.y); o.z = f2bf(v.z); o.w = f2bf(v.w);
    *(ushort4*)(dst + (size_t)i * 4) = o;
  }
}

// ---------------- bf16 GEMM, C = A @ B^T (m97 structure) ----------------
// A: (M,K) bf16 row-major; Bw: (N,K) bf16 row-major; C: (M,N) OutT.
// grid = (M/128)*(N/128); 256 threads (4 waves, 2x2, each 64x64).
template <typename OutT>
__global__ __launch_bounds__(256) void gemm_bt(const uint16_t* __restrict__ A,
                                               const uint16_t* __restrict__ Bw,
                                               OutT* __restrict__ C, int Ndim, int Kdim) {
  constexpr int BK = 64;
  __shared__ uint16_t sA[128 * BK];
  __shared__ uint16_t sB[128 * BK];
  const int nbn = Ndim / 128;
  const int nwg = gridDim.x;
  // bijective XCD swizzle (m204)
  int q = nwg >> 3, r = nwg & 7;
  int xcd = blockIdx.x & 7, lin = blockIdx.x >> 3;
  int swz = (xcd < r ? xcd * (q + 1) : r * (q + 1) + (xcd - r) * q) + lin;
  const int bm = swz / nbn, bn = swz % nbn;

  const int tid = threadIdx.x;
  const int w = tid >> 6, lane = tid & 63;
  const int wr = w >> 1, wc = w & 1;
  const int srow = lane >> 3;          // row within 8-row chunk
  const int scol = (lane & 7) * 8;     // bf16 col offset (16B granules)
  const uint16_t* Ab = A + (size_t)(bm * 128) * Kdim + scol;
  const uint16_t* Bb = Bw + (size_t)(bn * 128) * Kdim + scol;

  f32x4 acc[4][4] = {};

  for (int k0 = 0; k0 < Kdim; k0 += BK) {
#pragma unroll
    for (int cc = 0; cc < 4; ++cc) {
      int ch = w * 4 + cc;                 // chunk 0..15 (8 rows each)
      int row = ch * 8 + srow;
      gload16(sA + ch * 512, Ab + (size_t)row * Kdim + k0);
      gload16(sB + ch * 512, Bb + (size_t)row * Kdim + k0);
    }
    __syncthreads();
    const int lr = lane & 15;
    const int lk0 = (lane >> 4) * 8;
#pragma unroll
    for (int kk = 0; kk < 2; ++kk) {
      bf16x8 af[4], bfr[4];
      const int lk = lk0 + kk * 32;
#pragma unroll
      for (int m = 0; m < 4; ++m)
        af[m] = *(const bf16x8*)&sA[(wr * 64 + m * 16 + lr) * BK + lk];
#pragma unroll
      for (int n = 0; n < 4; ++n)
        bfr[n] = *(const bf16x8*)&sB[(wc * 64 + n * 16 + lr) * BK + lk];
#pragma unroll
      for (int m = 0; m < 4; ++m)
#pragma unroll
        for (int n = 0; n < 4; ++n)
          acc[m][n] = __builtin_amdgcn_mfma_f32_16x16x32_bf16(af[m], bfr[n], acc[m][n], 0, 0, 0);
    }
    __syncthreads();
  }

  const int lr = lane & 15;
  const int r0 = (lane >> 4) * 4;
#pragma unroll
  for (int m = 0; m < 4; ++m)
#pragma unroll
    for (int n = 0; n < 4; ++n) {
      int col = bn * 128 + wc * 64 + n * 16 + lr;
#pragma unroll
      for (int j = 0; j < 4; ++j) {
        int row = bm * 128 + wr * 64 + m * 16 + r0 + j;
        float val = acc[m][n][j];
        if constexpr (sizeof(OutT) == 2)
          C[(size_t)row * Ndim + col] = (OutT)f2bf(val);
        else
          C[(size_t)row * Ndim + col] = (OutT)val;
      }
    }
}

// ---------------- alpha/beta (fp32, sigmoid fused) ----------------
// block = one token row; outputs [row][0..15]=alpha, [16..31]=beta/sqrt(HD)
__global__ __launch_bounds__(256) void alphabeta_kernel(const float* __restrict__ x,
                                                        const float* __restrict__ aw,
                                                        const float* __restrict__ abias,
                                                        const float* __restrict__ bw,
                                                        const float* __restrict__ bbias,
                                                        float* __restrict__ out) {
  __shared__ float xrow[Dc];
  const int row = blockIdx.x;
  const float* xp = x + (size_t)row * Dc;
  for (int i = threadIdx.x; i < Dc; i += 256) xrow[i] = xp[i];
  __syncthreads();
  const int o = threadIdx.x >> 3, lg = threadIdx.x & 7;
  const float* wrow = (o < 16) ? (aw + (size_t)o * Dc) : (bw + (size_t)(o - 16) * Dc);
  float s = 0.f;
  for (int i = lg * 4; i < Dc; i += 32) {
    float4 xv = *(const float4*)&xrow[i];
    float4 wv = *(const float4*)&wrow[i];
    s += xv.x * wv.x + xv.y * wv.y + xv.z * wv.z + xv.w * wv.w;
  }
  s += __shfl_xor(s, 1); s += __shfl_xor(s, 2); s += __shfl_xor(s, 4);
  if (lg == 0) {
    float bias = (o < 16) ? abias[o] : bbias[o - 16];
    float sig = sigmoidf_(s + bias);
    if (o >= 16) sig *= 0.08838834764831845f;   // 1/sqrt(128)
    out[(size_t)row * 32 + o] = sig;
  }
}

// ---------------- causal depthwise conv (k=4) + head RMSNorm ----------------
// one wave per (b,t,kvh); lane handles channels c and c+64
__global__ __launch_bounds__(256) void convnorm_kernel(const uint16_t* __restrict__ C1,
                                                       const float* __restrict__ qcw,
                                                       const float* __restrict__ kcw,
                                                       const float* __restrict__ nqw,
                                                       const float* __restrict__ nkw,
                                                       uint16_t* __restrict__ Qn,
                                                       uint16_t* __restrict__ Kn) {
  const int wid = blockIdx.x * 4 + (threadIdx.x >> 6);
  const int lane = threadIdx.x & 63;
  const int kvh = wid & 7;
  const int t = (wid >> 3) & (Sc - 1);
  const int b = wid >> 15;
  float qv[2], kv[2];
#pragma unroll
  for (int half = 0; half < 2; ++half) {
    const int c = lane + half * 64;
    const int ch = kvh * HDc + c;
    float qs = 0.f, ks = 0.f;
#pragma unroll
    for (int j = 0; j < 4; ++j) {
      int tt = t - 3 + j;
      if (tt >= 0) {
        size_t rb = (size_t)(b * Sc + tt) * NCATc;
        qs = fmaf(bf2f(C1[rb + ch]), qcw[ch * 4 + j], qs);
        ks = fmaf(bf2f(C1[rb + 1024 + ch]), kcw[ch * 4 + j], ks);
      }
    }
    qv[half] = qs; kv[half] = ks;
  }
  float sq = qv[0] * qv[0] + qv[1] * qv[1];
  float sk = kv[0] * kv[0] + kv[1] * kv[1];
#pragma unroll
  for (int m = 1; m < 64; m <<= 1) { sq += __shfl_xor(sq, m); sk += __shfl_xor(sk, m); }
  const float rq = rsqrtf(sq * (1.f / HDc) + EPSc);
  const float rk = rsqrtf(sk * (1.f / HDc) + EPSc);
#pragma unroll
  for (int half = 0; half < 2; ++half) {
    const int c = lane + half * 64;
    size_t oidx = (size_t)(b * Sc + t) * DQKc + kvh * HDc + c;
    Qn[oidx] = f2bf(nqw[c] * qv[half] * rq);
    Kn[oidx] = f2bf(nkw[c] * kv[half] * rk);
  }
}

// ---------------- gated delta-rule scan ----------------
// block = (b, h, v-slice of 16); thread (v=tid>>4, g=tid&15) owns S[g*8..g*8+8)[vcol]
__global__ __launch_bounds__(256) void scan_kernel(const uint16_t* __restrict__ Qn,
                                                   const uint16_t* __restrict__ Kn,
                                                   const uint16_t* __restrict__ C1,
                                                   const float* __restrict__ ab,
                                                   float* __restrict__ O) {
  const int bid = blockIdx.x;
  const int sl = bid & 7;
  const int h = (bid >> 3) & 15;
  const int b = bid >> 7;
  const int kh = h >> 1;                  // GQA: head h uses kv-head h/2
  const int v = threadIdx.x >> 4;
  const int g = threadIdx.x & 15;
  const int vcol = sl * 16 + v;

  const uint16_t* kp = Kn + (size_t)b * Sc * DQKc + kh * HDc + g * 8;
  const uint16_t* qp = Qn + (size_t)b * Sc * DQKc + kh * HDc + g * 8;
  const uint16_t* vp = C1 + (size_t)b * Sc * NCATc + 2048 + h * HDc + vcol;
  const float* abp = ab + (size_t)b * Sc * 32 + h;
  float* op = O + (size_t)b * Sc * DVc + h * HDc + vcol;

  float Srg[8];
#pragma unroll
  for (int i = 0; i < 8; ++i) Srg[i] = 0.f;

  uint4 kcur = *(const uint4*)kp;
  uint4 qcur = *(const uint4*)qp;
  uint16_t vcur = *vp;
  float acur = abp[0];
  float bcur = abp[16];

  for (int t = 0; t < Sc; ++t) {
    uint4 knx = kcur, qnx = qcur; uint16_t vnx = vcur; float anx = acur, bnx = bcur;
    if (t + 1 < Sc) {                       // prefetch next step
      size_t r1 = (size_t)(t + 1);
      knx = *(const uint4*)(kp + r1 * DQKc);
      qnx = *(const uint4*)(qp + r1 * DQKc);
      vnx = vp[r1 * NCATc];
      anx = abp[r1 * 32];
      bnx = abp[r1 * 32 + 16];
    }
    float kf[8], qf[8];
    unpack8(kcur, kf);
    unpack8(qcur, qf);
    float pr = 0.f;
#pragma unroll
    for (int i = 0; i < 8; ++i) pr = fmaf(kf[i], Srg[i], pr);
    pr = red16(pr);                         // pred[vcol] = k . S[:,vcol]
    float delta = bf2f(vcur) - pr;
    float bd = bcur * delta;
    float ov = 0.f;
#pragma unroll
    for (int i = 0; i < 8; ++i) {
      Srg[i] = fmaf(acur, Srg[i], bd * kf[i]);   // S = a*S + (b*delta)*k
      ov = fmaf(qf[i], Srg[i], ov);
    }
    ov = red16(ov);                         // o[vcol] = q . S[:,vcol]
    if (g == 0) op[(size_t)t * DVc] = ov;
    kcur = knx; qcur = qnx; vcur = vnx; acur = anx; bcur = bnx;
  }
}

// ---------------- g = sigmoid(Graw); gOb = bf16(g * O) ----------------
__global__ __launch_bounds__(256) void gmul_kernel(const uint16_t* __restrict__ C1,
                                                   const float* __restrict__ O,
                                                   uint16_t* __restrict__ gOb) {
  int i = blockIdx.x * blockDim.x + threadIdx.x;
  const int n4 = Mc * DVc / 4;
  const int stride = gridDim.x * blockDim.x;
  for (; i < n4; i += stride) {
    int idx = i * 4;
    int row = idx >> 11;
    int col = idx & (DVc - 1);
    ushort4 gr = *(const ushort4*)&C1[(size_t)row * NCATc + 4096 + col];
    float4 ov = *(const float4*)&O[idx];
    ushort4 r;
    r.x = f2bf(sigmoidf_(bf2f(gr.x)) * ov.x);
    r.y = f2bf(sigmoidf_(bf2f(gr.y)) * ov.y);
    r.z = f2bf(sigmoidf_(bf2f(gr.z)) * ov.z);
    r.w = f2bf(sigmoidf_(bf2f(gr.w)) * ov.w);
    *(ushort4*)&gOb[idx] = r;
  }
}

extern "C" void kernel_launch(void* const* d_in, const int* in_sizes, int n_in,
                              void* d_out, int out_size, void* d_ws, size_t ws_size,
                              hipStream_t stream) {
  (void)in_sizes; (void)n_in; (void)out_size; (void)ws_size;
  const float* x     = (const float*)d_in[0];
  const float* wq    = (const float*)d_in[1];
  const float* wk    = (const float*)d_in[2];
  const float* wv    = (const float*)d_in[3];
  const float* wo    = (const float*)d_in[4];
  const float* qcw   = (const float*)d_in[5];
  const float* kcw   = (const float*)d_in[6];
  const float* aw    = (const float*)d_in[7];
  const float* abias = (const float*)d_in[8];
  const float* bw    = (const float*)d_in[9];
  const float* bbias = (const float*)d_in[10];
  const float* gw    = (const float*)d_in[11];
  const float* nqw   = (const float*)d_in[12];
  const float* nkw   = (const float*)d_in[13];

  // workspace layout (bytes), total ~193 MiB
  uint8_t* ws = (uint8_t*)d_ws;
  uint16_t* xb   = (uint16_t*)(ws);                 //  33,554,432  x bf16 (reused as gOb)
  uint16_t* wcat = (uint16_t*)(ws + 33554432);      //  25,165,824  [wq;wk;wv;g_w] bf16
  uint16_t* wob  = (uint16_t*)(ws + 58720256);      //   8,388,608  wo bf16
  uint16_t* c1   = (uint16_t*)(ws + 67108864);      // 100,663,296  x@Wcat^T bf16 (8192x6144)
  float*    abuf = (float*)   (ws + 167772160);     //   1,048,576  alpha|beta
  uint16_t* qn   = (uint16_t*)(ws + 168820736);     //  16,777,216  normed Q bf16
  uint16_t* kn   = (uint16_t*)(ws + 185597952);     //  16,777,216  normed K bf16
  uint16_t* gob  = xb;                              // reuse (xb dead after GEMM1)
  float* obuf = (float*)d_out;                      // d_out doubles as O scratch

  cast_kernel<<<2048, 256, 0, stream>>>(x, xb, Mc * Dc / 4);
  cast_kernel<<<1024, 256, 0, stream>>>(wq, wcat, DQKc * Dc / 4);
  cast_kernel<<<1024, 256, 0, stream>>>(wk, wcat + DQKc * Dc, DQKc * Dc / 4);
  cast_kernel<<<1024, 256, 0, stream>>>(wv, wcat + 2 * DQKc * Dc, DVc * Dc / 4);
  cast_kernel<<<1024, 256, 0, stream>>>(gw, wcat + 2 * DQKc * Dc + DVc * Dc, DVc * Dc / 4);
  cast_kernel<<<1024, 256, 0, stream>>>(wo, wob, DVc * Dc / 4);

  gemm_bt<uint16_t><<<3072, 256, 0, stream>>>(xb, wcat, c1, NCATc, Dc);         // QKVG
  alphabeta_kernel<<<8192, 256, 0, stream>>>(x, aw, abias, bw, bbias, abuf);
  convnorm_kernel<<<16384, 256, 0, stream>>>(c1, qcw, kcw, nqw, nkw, qn, kn);
  scan_kernel<<<256, 256, 0, stream>>>(qn, kn, c1, abuf, obuf);                 // O -> d_out
  gmul_kernel<<<2048, 256, 0, stream>>>(c1, obuf, gob);                         // gOb -> ws
  gemm_bt<float><<<1024, 256, 0, stream>>>(gob, wob, (float*)d_out, DVc, Dc);   // final
}

// Round 2
// 1632.506 us; speedup vs baseline: 1.3135x; 1.3135x over previous
//
#include <hip/hip_runtime.h>
#include <stdint.h>

#define DEV static __device__ __forceinline__

typedef __bf16 bf16x8 __attribute__((ext_vector_type(8)));
typedef float f32x4 __attribute__((ext_vector_type(4)));

constexpr int Bc = 2, Sc = 4096, Dc = 2048, Hc = 16, KVHc = 8, HDc = 128;
constexpr int DQKc = 1024, DVc = 2048;
constexpr int Mc = Bc * Sc;       // 8192 rows
constexpr int NCATc = 6144;       // Q(1024) | K(1024) | V(2048) | Graw(2048)
constexpr int CT = 8;             // scan chunk length
constexpr int NCH = Sc / CT;      // 512 chunks per sequence
constexpr float EPSc = 1e-6f;

DEV uint16_t f2bf(float f) {
  uint32_t u = __float_as_uint(f);
  u += 0x7FFFu + ((u >> 16) & 1u);   // RNE
  return (uint16_t)(u >> 16);
}
DEV float bf2f(uint16_t h) { return __uint_as_float(((uint32_t)h) << 16); }
DEV float sigmoidf_(float z) { return 1.0f / (1.0f + __expf(-z)); }

DEV void unpack8(uint4 u, float* f) {
  f[0] = __uint_as_float(u.x << 16); f[1] = __uint_as_float(u.x & 0xFFFF0000u);
  f[2] = __uint_as_float(u.y << 16); f[3] = __uint_as_float(u.y & 0xFFFF0000u);
  f[4] = __uint_as_float(u.z << 16); f[5] = __uint_as_float(u.z & 0xFFFF0000u);
  f[6] = __uint_as_float(u.w << 16); f[7] = __uint_as_float(u.w & 0xFFFF0000u);
}

// sum across each 16-lane DPP row via row_ror 1,2,4,8
DEV float red16(float x) {
  x += __int_as_float(__builtin_amdgcn_update_dpp(0, __float_as_int(x), 0x121, 0xF, 0xF, true));
  x += __int_as_float(__builtin_amdgcn_update_dpp(0, __float_as_int(x), 0x122, 0xF, 0xF, true));
  x += __int_as_float(__builtin_amdgcn_update_dpp(0, __float_as_int(x), 0x124, 0xF, 0xF, true));
  x += __int_as_float(__builtin_amdgcn_update_dpp(0, __float_as_int(x), 0x128, 0xF, 0xF, true));
  return x;
}

DEV void gload16(void* lds, const void* g) {
  auto gp = (const __attribute__((address_space(1))) uint32_t*)(uintptr_t)g;
  auto lp = (__attribute__((address_space(3))) uint32_t*)(uint32_t)(uintptr_t)lds;
  __builtin_amdgcn_global_load_lds(gp, lp, 16, 0, 0);
}

// ---------------- f32 -> bf16 cast ----------------
__global__ __launch_bounds__(256) void cast_kernel(const float* __restrict__ src,
                                                   uint16_t* __restrict__ dst, int n4) {
  int i = blockIdx.x * blockDim.x + threadIdx.x;
  int stride = gridDim.x * blockDim.x;
  for (; i < n4; i += stride) {
    float4 v = *(const float4*)(src + (size_t)i * 4);
    ushort4 o;
    o.x = f2bf(v.x); o.y = f2bf(v.y); o.z = f2bf(v.z); o.w = f2bf(v.w);
    *(ushort4*)(dst + (size_t)i * 4) = o;
  }
}

// ---------------- bf16 GEMM, C = A @ B^T (m97 structure) ----------------
template <typename OutT>
__global__ __launch_bounds__(256) void gemm_bt(const uint16_t* __restrict__ A,
                                               const uint16_t* __restrict__ Bw,
                                               OutT* __restrict__ C, int Ndim, int Kdim) {
  constexpr int BK = 64;
  __shared__ uint16_t sA[128 * BK];
  __shared__ uint16_t sB[128 * BK];
  const int nbn = Ndim / 128;
  const int nwg = gridDim.x;
  int q = nwg >> 3, r = nwg & 7;
  int xcd = blockIdx.x & 7, lin = blockIdx.x >> 3;
  int swz = (xcd < r ? xcd * (q + 1) : r * (q + 1) + (xcd - r) * q) + lin;
  const int bm = swz / nbn, bn = swz % nbn;

  const int tid = threadIdx.x;
  const int w = tid >> 6, lane = tid & 63;
  const int wr = w >> 1, wc = w & 1;
  const int srow = lane >> 3;
  const int scol = (lane & 7) * 8;
  const uint16_t* Ab = A + (size_t)(bm * 128) * Kdim + scol;
  const uint16_t* Bb = Bw + (size_t)(bn * 128) * Kdim + scol;

  f32x4 acc[4][4] = {};

  for (int k0 = 0; k0 < Kdim; k0 += BK) {
#pragma unroll
    for (int cc = 0; cc < 4; ++cc) {
      int ch = w * 4 + cc;
      int row = ch * 8 + srow;
      gload16(sA + ch * 512, Ab + (size_t)row * Kdim + k0);
      gload16(sB + ch * 512, Bb + (size_t)row * Kdim + k0);
    }
    __syncthreads();
    const int lr = lane & 15;
    const int lk0 = (lane >> 4) * 8;
#pragma unroll
    for (int kk = 0; kk < 2; ++kk) {
      bf16x8 af[4], bfr[4];
      const int lk = lk0 + kk * 32;
#pragma unroll
      for (int m = 0; m < 4; ++m)
        af[m] = *(const bf16x8*)&sA[(wr * 64 + m * 16 + lr) * BK + lk];
#pragma unroll
      for (int n = 0; n < 4; ++n)
        bfr[n] = *(const bf16x8*)&sB[(wc * 64 + n * 16 + lr) * BK + lk];
#pragma unroll
      for (int m = 0; m < 4; ++m)
#pragma unroll
        for (int n = 0; n < 4; ++n)
          acc[m][n] = __builtin_amdgcn_mfma_f32_16x16x32_bf16(af[m], bfr[n], acc[m][n], 0, 0, 0);
    }
    __syncthreads();
  }

  const int lr = lane & 15;
  const int r0 = (lane >> 4) * 4;
#pragma unroll
  for (int m = 0; m < 4; ++m)
#pragma unroll
    for (int n = 0; n < 4; ++n) {
      int col = bn * 128 + wc * 64 + n * 16 + lr;
#pragma unroll
      for (int j = 0; j < 4; ++j) {
        int row = bm * 128 + wr * 64 + m * 16 + r0 + j;
        float val = acc[m][n][j];
        if constexpr (sizeof(OutT) == 2)
          C[(size_t)row * Ndim + col] = (OutT)f2bf(val);
        else
          C[(size_t)row * Ndim + col] = (OutT)val;
      }
    }
}

// ---------------- alpha/beta (fp32, sigmoid fused) ----------------
__global__ __launch_bounds__(256) void alphabeta_kernel(const float* __restrict__ x,
                                                        const float* __restrict__ aw,
                                                        const float* __restrict__ abias,
                                                        const float* __restrict__ bw,
                                                        const float* __restrict__ bbias,
                                                        float* __restrict__ out) {
  __shared__ float xrow[Dc];
  const int row = blockIdx.x;
  const float* xp = x + (size_t)row * Dc;
  for (int i = threadIdx.x; i < Dc; i += 256) xrow[i] = xp[i];
  __syncthreads();
  const int o = threadIdx.x >> 3, lg = threadIdx.x & 7;
  const float* wrow = (o < 16) ? (aw + (size_t)o * Dc) : (bw + (size_t)(o - 16) * Dc);
  float s = 0.f;
  for (int i = lg * 4; i < Dc; i += 32) {
    float4 xv = *(const float4*)&xrow[i];
    float4 wv = *(const float4*)&wrow[i];
    s += xv.x * wv.x + xv.y * wv.y + xv.z * wv.z + xv.w * wv.w;
  }
  s += __shfl_xor(s, 1); s += __shfl_xor(s, 2); s += __shfl_xor(s, 4);
  if (lg == 0) {
    float bias = (o < 16) ? abias[o] : bbias[o - 16];
    float sig = sigmoidf_(s + bias);
    if (o >= 16) sig *= 0.08838834764831845f;   // 1/sqrt(128)
    out[(size_t)row * 32 + o] = sig;
  }
}

// ---------------- causal depthwise conv (k=4) + head RMSNorm ----------------
__global__ __launch_bounds__(256) void convnorm_kernel(const uint16_t* __restrict__ C1,
                                                       const float* __restrict__ qcw,
                                                       const float* __restrict__ kcw,
                                                       const float* __restrict__ nqw,
                                                       const float* __restrict__ nkw,
                                                       uint16_t* __restrict__ Qn,
                                                       uint16_t* __restrict__ Kn) {
  const int wid = blockIdx.x * 4 + (threadIdx.x >> 6);
  const int lane = threadIdx.x & 63;
  const int kvh = wid & 7;
  const int t = (wid >> 3) & (Sc - 1);
  const int b = wid >> 15;
  float qv[2], kv[2];
#pragma unroll
  for (int half = 0; half < 2; ++half) {
    const int c = lane + half * 64;
    const int ch = kvh * HDc + c;
    float qs = 0.f, ks = 0.f;
#pragma unroll
    for (int j = 0; j < 4; ++j) {
      int tt = t - 3 + j;
      if (tt >= 0) {
        size_t rb = (size_t)(b * Sc + tt) * NCATc;
        qs = fmaf(bf2f(C1[rb + ch]), qcw[ch * 4 + j], qs);
        ks = fmaf(bf2f(C1[rb + 1024 + ch]), kcw[ch * 4 + j], ks);
      }
    }
    qv[half] = qs; kv[half] = ks;
  }
  float sq = qv[0] * qv[0] + qv[1] * qv[1];
  float sk = kv[0] * kv[0] + kv[1] * kv[1];
#pragma unroll
  for (int m = 1; m < 64; m <<= 1) { sq += __shfl_xor(sq, m); sk += __shfl_xor(sk, m); }
  const float rq = rsqrtf(sq * (1.f / HDc) + EPSc);
  const float rk = rsqrtf(sk * (1.f / HDc) + EPSc);
#pragma unroll
  for (int half = 0; half < 2; ++half) {
    const int c = lane + half * 64;
    size_t oidx = (size_t)(b * Sc + t) * DQKc + kvh * HDc + c;
    Qn[oidx] = f2bf(nqw[c] * qv[half] * rq);
    Kn[oidx] = f2bf(nkw[c] * kv[half] * rk);
  }
}

// ---------------- per-chunk score/coefficient precompute ----------------
// one wave per chunk (b,h,c). Output per chunk (stride 256 floats):
//   [0..63]    w[i][j]  = (G_{i-1}/G_j) b_j (k_j.k_i)   (j<i, else 0)
//   [64..127]  m[i][j]  = (G_i/G_j)    b_j (k_j.q_i)    (j<=i, else 0)
//   [128..135] gA[i] = G_{i-1}
//   [136..143] gB[i] = G_i
//   [144..151] gC[i] = (G_{T-1}/G_i) b_i
__global__ __launch_bounds__(256) void scores_kernel(const uint16_t* __restrict__ Qn,
                                                     const uint16_t* __restrict__ Kn,
                                                     const float* __restrict__ ab,
                                                     float* __restrict__ coef) {
  __shared__ uint16_t sKQ[4][2][CT][128];
  const int wv = threadIdx.x >> 6, lane = threadIdx.x & 63;
  const int wchunk = blockIdx.x * 4 + wv;
  const int c = wchunk & (NCH - 1);
  const int h = (wchunk >> 9) & 15;
  const int b = wchunk >> 13;
  const int kh = h >> 1;
  const int t0 = c * CT;

  {  // stage K,Q rows (4 x 1KB, full-wave global_load_lds)
    const int r = lane >> 4, s = lane & 15;
    size_t rowb = (size_t)(b * Sc + t0 + r) * DQKc + kh * HDc + s * 8;
    gload16(&sKQ[wv][0][0][0], Kn + rowb);
    gload16(&sKQ[wv][0][4][0], Kn + rowb + (size_t)4 * DQKc);
    gload16(&sKQ[wv][1][0][0], Qn + rowb);
    gload16(&sKQ[wv][1][4][0], Qn + rowb + (size_t)4 * DQKc);
  }
  float av[CT], bv[CT];
  const float* abp = ab + (size_t)(b * Sc + t0) * 32 + h;
#pragma unroll
  for (int r = 0; r < CT; ++r) { av[r] = abp[r * 32]; bv[r] = abp[r * 32 + 16]; }
  __syncthreads();

  const int i = lane >> 3, j = lane & 7;
  float kk = 0.f, qk = 0.f;
#pragma unroll
  for (int t = 0; t < 16; ++t) {
    int s = (t + lane) & 15;                       // staggered: avoids bank conflicts
    uint4 ukj = *(const uint4*)&sKQ[wv][0][j][s * 8];
    uint4 uki = *(const uint4*)&sKQ[wv][0][i][s * 8];
    uint4 uqi = *(const uint4*)&sKQ[wv][1][i][s * 8];
    float fj[8], fi[8], fq[8];
    unpack8(ukj, fj); unpack8(uki, fi); unpack8(uqi, fq);
#pragma unroll
    for (int e = 0; e < 8; ++e) { kk = fmaf(fj[e], fi[e], kk); qk = fmaf(fj[e], fq[e], qk); }
  }
  float G[CT];
  G[0] = av[0];
#pragma unroll
  for (int r = 1; r < CT; ++r) G[r] = G[r - 1] * av[r];
  const float gAi = (i == 0) ? 1.f : G[i - 1];
  float* cf = coef + (size_t)wchunk * 256;
  cf[i * 8 + j]      = (j < i)  ? gAi / G[j] * bv[j] * kk : 0.f;
  cf[64 + i * 8 + j] = (j <= i) ? G[i] / G[j] * bv[j] * qk : 0.f;
  if (j == 0) {
    cf[128 + i] = gAi;
    cf[136 + i] = G[i];
    cf[144 + i] = (G[CT - 1] / G[i]) * bv[i];
  }
}

// ---------------- chunked gated delta-rule scan (T=8) ----------------
// block = (b, h, v-slice of 16); thread (v=tid>>4, g=tid&15) owns S[g*8..g*8+8)[vcol]
__global__ __launch_bounds__(256) void scan_kernel(const uint16_t* __restrict__ Qn,
                                                   const uint16_t* __restrict__ Kn,
                                                   const uint16_t* __restrict__ C1,
                                                   const float* __restrict__ coef,
                                                   float* __restrict__ O) {
  __shared__ uint16_t Kb[2][CT][128];
  __shared__ uint16_t Qb[2][CT][128];
  __shared__ uint16_t Vb[2][CT][16];
  __shared__ float    Cf[2][256];

  const int bid = blockIdx.x;
  const int sl = bid & 7, h = (bid >> 3) & 15, b = bid >> 7;
  const int kh = h >> 1;
  const int tid = threadIdx.x, wv = tid >> 6, lane = tid & 63;
  const int v = tid >> 4, g = tid & 15;

  const size_t kqrow0 = (size_t)(b * Sc) * DQKc + kh * HDc;
  const size_t vbb = (size_t)(b * Sc) * NCATc + 2048 + h * HDc + sl * 16;
  const float* cfp = coef + (size_t)(b * Hc + h) * NCH * 256;
  float* op = O + (size_t)(b * Sc) * DVc + h * HDc + sl * 16 + v;

  const int sr = lane >> 4, ss = lane & 15;
  auto STAGE_KQC = [&](int c, int bf) {
    size_t rowb = kqrow0 + (size_t)(c * CT + sr) * DQKc + ss * 8;
    if (wv == 0) gload16(&Kb[bf][0][0], Kn + rowb);
    else if (wv == 1) gload16(&Kb[bf][4][0], Kn + rowb + (size_t)4 * DQKc);
    else if (wv == 2) gload16(&Qb[bf][0][0], Qn + rowb);
    else {
      gload16(&Qb[bf][4][0], Qn + rowb + (size_t)4 * DQKc);
      gload16(&Cf[bf][0], cfp + (size_t)c * 256 + lane * 4);
    }
  };

  float S[8] = {};
  uint4 vtmp = {0, 0, 0, 0};

  // prologue: stage chunk 0
  STAGE_KQC(0, 0);
  if (tid < 16) {
    vtmp = *(const uint4*)(C1 + vbb + (size_t)(tid >> 1) * NCATc + (tid & 1) * 8);
    *(uint4*)&Vb[0][tid >> 1][(tid & 1) * 8] = vtmp;
  }
  __syncthreads();

  int buf = 0;
  for (int c = 0; c < NCH; ++c) {
    const int t0 = c * CT;
    const bool pre = (c + 1 < NCH);
    if (pre) {
      STAGE_KQC(c + 1, buf ^ 1);
      if (tid < 16)
        vtmp = *(const uint4*)(C1 + vbb + (size_t)((c + 1) * CT + (tid >> 1)) * NCATc + (tid & 1) * 8);
    }

    // ---- compute chunk c from buf ----
    uint4 kr[CT], qr[CT];
#pragma unroll
    for (int r = 0; r < CT; ++r) {
      kr[r] = *(const uint4*)&Kb[buf][r][g * 8];
      qr[r] = *(const uint4*)&Qb[buf][r][g * 8];
    }
    float vv[CT];
#pragma unroll
    for (int r = 0; r < CT; ++r) vv[r] = bf2f(Vb[buf][r][v]);
    float gA[8], gB[8], gC[8];
    *(float4*)&gA[0] = *(const float4*)&Cf[buf][128];
    *(float4*)&gA[4] = *(const float4*)&Cf[buf][132];
    *(float4*)&gB[0] = *(const float4*)&Cf[buf][136];
    *(float4*)&gB[4] = *(const float4*)&Cf[buf][140];
    *(float4*)&gC[0] = *(const float4*)&Cf[buf][144];
    *(float4*)&gC[4] = *(const float4*)&Cf[buf][148];

    float pk[CT], pq[CT];
#pragma unroll
    for (int r = 0; r < CT; ++r) {
      float kf[8], qf[8];
      unpack8(kr[r], kf); unpack8(qr[r], qf);
      float a = 0.f, bq = 0.f;
#pragma unroll
      for (int e = 0; e < 8; ++e) { a = fmaf(kf[e], S[e], a); bq = fmaf(qf[e], S[e], bq); }
      pk[r] = red16(a); pq[r] = red16(bq);
    }

    float dl[8] = {0.f, 0.f, 0.f, 0.f, 0.f, 0.f, 0.f, 0.f};
#pragma unroll
    for (int i = 0; i < CT; ++i) {
      float4 w0 = *(const float4*)&Cf[buf][i * 8];
      float4 w1 = *(const float4*)&Cf[buf][i * 8 + 4];
      float di = fmaf(-gA[i], pk[i], vv[i]);
      di -= w0.x * dl[0] + w0.y * dl[1] + w0.z * dl[2] + w0.w * dl[3]
          + w1.x * dl[4] + w1.y * dl[5] + w1.z * dl[6] + w1.w * dl[7];
      dl[i] = di;
    }
#pragma unroll
    for (int i = 0; i < CT; ++i) {
      float4 m0 = *(const float4*)&Cf[buf][64 + i * 8];
      float4 m1 = *(const float4*)&Cf[buf][64 + i * 8 + 4];
      float oi = fmaf(gB[i], pq[i],
                 m0.x * dl[0] + m0.y * dl[1] + m0.z * dl[2] + m0.w * dl[3]
               + m1.x * dl[4] + m1.y * dl[5] + m1.z * dl[6] + m1.w * dl[7]);
      if (g == 0) op[(size_t)(t0 + i) * DVc] = oi;
    }
    const float gT = gB[7];
    float cc2[8];
#pragma unroll
    for (int i = 0; i < CT; ++i) cc2[i] = gC[i] * dl[i];
#pragma unroll
    for (int e = 0; e < 8; ++e) S[e] *= gT;
#pragma unroll
    for (int r = 0; r < CT; ++r) {
      float kf[8];
      unpack8(kr[r], kf);
#pragma unroll
      for (int e = 0; e < 8; ++e) S[e] = fmaf(cc2[r], kf[e], S[e]);
    }
    // ---- end compute ----

    if (pre && tid < 16)
      *(uint4*)&Vb[buf ^ 1][tid >> 1][(tid & 1) * 8] = vtmp;
    __syncthreads();
    buf ^= 1;
  }
}

// ---------------- g = sigmoid(Graw); gOb = bf16(g * O) ----------------
__global__ __launch_bounds__(256) void gmul_kernel(const uint16_t* __restrict__ C1,
                                                   const float* __restrict__ O,
                                                   uint16_t* __restrict__ gOb) {
  int i = blockIdx.x * blockDim.x + threadIdx.x;
  const int n4 = Mc * DVc / 4;
  const int stride = gridDim.x * blockDim.x;
  for (; i < n4; i += stride) {
    int idx = i * 4;
    int row = idx >> 11;
    int col = idx & (DVc - 1);
    ushort4 gr = *(const ushort4*)&C1[(size_t)row * NCATc + 4096 + col];
    float4 ov = *(const float4*)&O[idx];
    ushort4 r;
    r.x = f2bf(sigmoidf_(bf2f(gr.x)) * ov.x);
    r.y = f2bf(sigmoidf_(bf2f(gr.y)) * ov.y);
    r.z = f2bf(sigmoidf_(bf2f(gr.z)) * ov.z);
    r.w = f2bf(sigmoidf_(bf2f(gr.w)) * ov.w);
    *(ushort4*)&gOb[idx] = r;
  }
}

extern "C" void kernel_launch(void* const* d_in, const int* in_sizes, int n_in,
                              void* d_out, int out_size, void* d_ws, size_t ws_size,
                              hipStream_t stream) {
  (void)in_sizes; (void)n_in; (void)out_size; (void)ws_size;
  const float* x     = (const float*)d_in[0];
  const float* wq    = (const float*)d_in[1];
  const float* wk    = (const float*)d_in[2];
  const float* wv    = (const float*)d_in[3];
  const float* wo    = (const float*)d_in[4];
  const float* qcw   = (const float*)d_in[5];
  const float* kcw   = (const float*)d_in[6];
  const float* aw    = (const float*)d_in[7];
  const float* abias = (const float*)d_in[8];
  const float* bw    = (const float*)d_in[9];
  const float* bbias = (const float*)d_in[10];
  const float* gw    = (const float*)d_in[11];
  const float* nqw   = (const float*)d_in[12];
  const float* nkw   = (const float*)d_in[13];

  // workspace layout (bytes), total ~193 MiB
  uint8_t* ws = (uint8_t*)d_ws;
  uint16_t* xb   = (uint16_t*)(ws);                 //  33,554,432  x bf16 (reused: coef, then gOb)
  uint16_t* wcat = (uint16_t*)(ws + 33554432);      //  25,165,824  [wq;wk;wv;g_w] bf16
  uint16_t* wob  = (uint16_t*)(ws + 58720256);      //   8,388,608  wo bf16
  uint16_t* c1   = (uint16_t*)(ws + 67108864);      // 100,663,296  x@Wcat^T bf16 (8192x6144)
  float*    abuf = (float*)   (ws + 167772160);     //   1,048,576  alpha|beta
  uint16_t* qn   = (uint16_t*)(ws + 168820736);     //  16,777,216  normed Q bf16
  uint16_t* kn   = (uint16_t*)(ws + 185597952);     //  16,777,216  normed K bf16
  float*    coef = (float*)xb;                      // 16,777,216 (16384 chunks x 1KB) — xb dead after GEMM1
  uint16_t* gob  = xb;                              // reuse again after scan
  float* obuf = (float*)d_out;                      // d_out doubles as O scratch

  cast_kernel<<<2048, 256, 0, stream>>>(x, xb, Mc * Dc / 4);
  cast_kernel<<<1024, 256, 0, stream>>>(wq, wcat, DQKc * Dc / 4);
  cast_kernel<<<1024, 256, 0, stream>>>(wk, wcat + DQKc * Dc, DQKc * Dc / 4);
  cast_kernel<<<1024, 256, 0, stream>>>(wv, wcat + 2 * DQKc * Dc, DVc * Dc / 4);
  cast_kernel<<<1024, 256, 0, stream>>>(gw, wcat + 2 * DQKc * Dc + DVc * Dc, DVc * Dc / 4);
  cast_kernel<<<1024, 256, 0, stream>>>(wo, wob, DVc * Dc / 4);

  gemm_bt<uint16_t><<<3072, 256, 0, stream>>>(xb, wcat, c1, NCATc, Dc);         // QKVG
  alphabeta_kernel<<<8192, 256, 0, stream>>>(x, aw, abias, bw, bbias, abuf);
  convnorm_kernel<<<16384, 256, 0, stream>>>(c1, qcw, kcw, nqw, nkw, qn, kn);
  scores_kernel<<<4096, 256, 0, stream>>>(qn, kn, abuf, coef);                  // chunk coefs
  scan_kernel<<<256, 256, 0, stream>>>(qn, kn, c1, coef, obuf);                 // O -> d_out
  gmul_kernel<<<2048, 256, 0, stream>>>(c1, obuf, gob);                         // gOb -> ws
  gemm_bt<float><<<1024, 256, 0, stream>>>(gob, wob, (float*)d_out, DVc, Dc);   // final
}

// Round 3
// 938.324 us; speedup vs baseline: 2.2852x; 1.7398x over previous
//
#include <hip/hip_runtime.h>
#include <stdint.h>

#define DEV static __device__ __forceinline__

typedef __bf16 bf16x8 __attribute__((ext_vector_type(8)));
typedef float f32x4 __attribute__((ext_vector_type(4)));

constexpr int Bc = 2, Sc = 4096, Dc = 2048, Hc = 16, KVHc = 8, HDc = 128;
constexpr int DQKc = 1024, DVc = 2048;
constexpr int Mc = Bc * Sc;       // 8192 rows
constexpr int NCATc = 6144;       // Q(1024) | K(1024) | V(2048) | Graw(2048)
constexpr int CT = 64;            // scan chunk length
constexpr int NCH = Sc / CT;      // 64 chunks per sequence
constexpr int COEF_STRIDE = 16896; // bytes per chunk-head: M2 8KB | E 8KB | gA 256B | gB 256B
constexpr float EPSc = 1e-6f;

DEV uint16_t f2bf(float f) {
  uint32_t u = __float_as_uint(f);
  u += 0x7FFFu + ((u >> 16) & 1u);   // RNE
  return (uint16_t)(u >> 16);
}
DEV float bf2f(uint16_t h) { return __uint_as_float(((uint32_t)h) << 16); }
DEV float sigmoidf_(float z) { return 1.0f / (1.0f + __expf(-z)); }

DEV void gload16(void* lds, const void* g) {
  auto gp = (const __attribute__((address_space(1))) uint32_t*)(uintptr_t)g;
  auto lp = (__attribute__((address_space(3))) uint32_t*)(uint32_t)(uintptr_t)lds;
  __builtin_amdgcn_global_load_lds(gp, lp, 16, 0, 0);
}

// ---------------- f32 -> bf16 cast ----------------
__global__ __launch_bounds__(256) void cast_kernel(const float* __restrict__ src,
                                                   uint16_t* __restrict__ dst, int n4) {
  int i = blockIdx.x * blockDim.x + threadIdx.x;
  int stride = gridDim.x * blockDim.x;
  for (; i < n4; i += stride) {
    float4 v = *(const float4*)(src + (size_t)i * 4);
    ushort4 o;
    o.x = f2bf(v.x); o.y = f2bf(v.y); o.z = f2bf(v.z); o.w = f2bf(v.w);
    *(ushort4*)(dst + (size_t)i * 4) = o;
  }
}

// ---------------- bf16 GEMM, C = A @ B^T (m97 structure) ----------------
template <typename OutT>
__global__ __launch_bounds__(256) void gemm_bt(const uint16_t* __restrict__ A,
                                               const uint16_t* __restrict__ Bw,
                                               OutT* __restrict__ C, int Ndim, int Kdim) {
  constexpr int BK = 64;
  __shared__ uint16_t sA[128 * BK];
  __shared__ uint16_t sB[128 * BK];
  const int nbn = Ndim / 128;
  const int nwg = gridDim.x;
  int q = nwg >> 3, r = nwg & 7;
  int xcd = blockIdx.x & 7, lin = blockIdx.x >> 3;
  int swz = (xcd < r ? xcd * (q + 1) : r * (q + 1) + (xcd - r) * q) + lin;
  const int bm = swz / nbn, bn = swz % nbn;

  const int tid = threadIdx.x;
  const int w = tid >> 6, lane = tid & 63;
  const int wr = w >> 1, wc = w & 1;
  const int srow = lane >> 3;
  const int scol = (lane & 7) * 8;
  const uint16_t* Ab = A + (size_t)(bm * 128) * Kdim + scol;
  const uint16_t* Bb = Bw + (size_t)(bn * 128) * Kdim + scol;

  f32x4 acc[4][4] = {};

  for (int k0 = 0; k0 < Kdim; k0 += BK) {
#pragma unroll
    for (int cc = 0; cc < 4; ++cc) {
      int ch = w * 4 + cc;
      int row = ch * 8 + srow;
      gload16(sA + ch * 512, Ab + (size_t)row * Kdim + k0);
      gload16(sB + ch * 512, Bb + (size_t)row * Kdim + k0);
    }
    __syncthreads();
    const int lr = lane & 15;
    const int lk0 = (lane >> 4) * 8;
#pragma unroll
    for (int kk = 0; kk < 2; ++kk) {
      bf16x8 af[4], bfr[4];
      const int lk = lk0 + kk * 32;
#pragma unroll
      for (int m = 0; m < 4; ++m)
        af[m] = *(const bf16x8*)&sA[(wr * 64 + m * 16 + lr) * BK + lk];
#pragma unroll
      for (int n = 0; n < 4; ++n)
        bfr[n] = *(const bf16x8*)&sB[(wc * 64 + n * 16 + lr) * BK + lk];
#pragma unroll
      for (int m = 0; m < 4; ++m)
#pragma unroll
        for (int n = 0; n < 4; ++n)
          acc[m][n] = __builtin_amdgcn_mfma_f32_16x16x32_bf16(af[m], bfr[n], acc[m][n], 0, 0, 0);
    }
    __syncthreads();
  }

  const int lr = lane & 15;
  const int r0 = (lane >> 4) * 4;
#pragma unroll
  for (int m = 0; m < 4; ++m)
#pragma unroll
    for (int n = 0; n < 4; ++n) {
      int col = bn * 128 + wc * 64 + n * 16 + lr;
#pragma unroll
      for (int j = 0; j < 4; ++j) {
        int row = bm * 128 + wr * 64 + m * 16 + r0 + j;
        float val = acc[m][n][j];
        if constexpr (sizeof(OutT) == 2)
          C[(size_t)row * Ndim + col] = (OutT)f2bf(val);
        else
          C[(size_t)row * Ndim + col] = (OutT)val;
      }
    }
}

// ---------------- alpha/beta (fp32, sigmoid fused) ----------------
__global__ __launch_bounds__(256) void alphabeta_kernel(const float* __restrict__ x,
                                                        const float* __restrict__ aw,
                                                        const float* __restrict__ abias,
                                                        const float* __restrict__ bw,
                                                        const float* __restrict__ bbias,
                                                        float* __restrict__ out) {
  __shared__ float xrow[Dc];
  const int row = blockIdx.x;
  const float* xp = x + (size_t)row * Dc;
  for (int i = threadIdx.x; i < Dc; i += 256) xrow[i] = xp[i];
  __syncthreads();
  const int o = threadIdx.x >> 3, lg = threadIdx.x & 7;
  const float* wrow = (o < 16) ? (aw + (size_t)o * Dc) : (bw + (size_t)(o - 16) * Dc);
  float s = 0.f;
  for (int i = lg * 4; i < Dc; i += 32) {
    float4 xv = *(const float4*)&xrow[i];
    float4 wv = *(const float4*)&wrow[i];
    s += xv.x * wv.x + xv.y * wv.y + xv.z * wv.z + xv.w * wv.w;
  }
  s += __shfl_xor(s, 1); s += __shfl_xor(s, 2); s += __shfl_xor(s, 4);
  if (lg == 0) {
    float bias = (o < 16) ? abias[o] : bbias[o - 16];
    float sig = sigmoidf_(s + bias);
    if (o >= 16) sig *= 0.08838834764831845f;   // 1/sqrt(128)
    out[(size_t)row * 32 + o] = sig;
  }
}

// ---------------- causal depthwise conv (k=4) + head RMSNorm ----------------
__global__ __launch_bounds__(256) void convnorm_kernel(const uint16_t* __restrict__ C1,
                                                       const float* __restrict__ qcw,
                                                       const float* __restrict__ kcw,
                                                       const float* __restrict__ nqw,
                                                       const float* __restrict__ nkw,
                                                       uint16_t* __restrict__ Qn,
                                                       uint16_t* __restrict__ Kn) {
  const int wid = blockIdx.x * 4 + (threadIdx.x >> 6);
  const int lane = threadIdx.x & 63;
  const int kvh = wid & 7;
  const int t = (wid >> 3) & (Sc - 1);
  const int b = wid >> 15;
  float qv[2], kv[2];
#pragma unroll
  for (int half = 0; half < 2; ++half) {
    const int c = lane + half * 64;
    const int ch = kvh * HDc + c;
    float qs = 0.f, ks = 0.f;
#pragma unroll
    for (int j = 0; j < 4; ++j) {
      int tt = t - 3 + j;
      if (tt >= 0) {
        size_t rb = (size_t)(b * Sc + tt) * NCATc;
        qs = fmaf(bf2f(C1[rb + ch]), qcw[ch * 4 + j], qs);
        ks = fmaf(bf2f(C1[rb + 1024 + ch]), kcw[ch * 4 + j], ks);
      }
    }
    qv[half] = qs; kv[half] = ks;
  }
  float sq = qv[0] * qv[0] + qv[1] * qv[1];
  float sk = kv[0] * kv[0] + kv[1] * kv[1];
#pragma unroll
  for (int m = 1; m < 64; m <<= 1) { sq += __shfl_xor(sq, m); sk += __shfl_xor(sk, m); }
  const float rq = rsqrtf(sq * (1.f / HDc) + EPSc);
  const float rk = rsqrtf(sk * (1.f / HDc) + EPSc);
#pragma unroll
  for (int half = 0; half < 2; ++half) {
    const int c = lane + half * 64;
    size_t oidx = (size_t)(b * Sc + t) * DQKc + kvh * HDc + c;
    Qn[oidx] = f2bf(nqw[c] * qv[half] * rq);
    Kn[oidx] = f2bf(nkw[c] * kv[half] * rk);
  }
}

// ---------------- per-chunk coefficient precompute (T=64) ----------------
// One block per (b,h,chunk). Outputs per chunk-head (COEF_STRIDE bytes):
//   M2 = M_s * Tinv        (64x64 bf16, row-major)      @ 0
//   E  = diag(gC) * Tinv   (64x64 bf16, row-major)      @ 8192
//   gA[i] = G_{i-1} (f32)  @ 16384 ; gB[i] = G_i (f32)  @ 16640
// where W[i][j] = (G_{i-1}/G_j) b_j (k_i.k_j) (j<i), Tinv = (I+W)^-1,
//       M_s[i][j] = (G_i/G_j) b_j (q_i.k_j) (j<=i), gC[i] = (G_63/G_i) b_i.
__global__ __launch_bounds__(256) void scores_kernel(const uint16_t* __restrict__ Qn,
                                                     const uint16_t* __restrict__ Kn,
                                                     const float* __restrict__ ab,
                                                     uint8_t* __restrict__ coef) {
  __shared__ __align__(16) char smem[72192];
  uint16_t* sK = (uint16_t*)smem;                 // [64][136] bf16
  float* Wtf = (float*)smem;                      // [64][68] f32 (alias, after KK/QK)
  uint16_t* sQ = (uint16_t*)(smem + 17408);       // [64][136] bf16
  uint16_t* sM2 = sQ;                             // reuse as [64][72] bf16 later
  uint16_t* Msh = (uint16_t*)(smem + 34816);      // [64][72]
  uint16_t* Msl = (uint16_t*)(smem + 44032);      // [64][72]
  uint16_t* Thh = (uint16_t*)(smem + 53248);      // Tinv^T hi [j][l]
  uint16_t* Thl = (uint16_t*)(smem + 62464);      // Tinv^T lo [j][l]
  float* Lb = (float*)(smem + 71680);             // [64]
  float* bbv = Lb + 64;                           // [64]

  const int bid = blockIdx.x;
  const int c = bid & 63, h = (bid >> 6) & 15, b = bid >> 10;
  const int kh = h >> 1;
  const int t0 = c * 64;
  const int tid = threadIdx.x;
  const int w = tid >> 6, l = tid & 63, lr = l & 15, lk = (l >> 4) * 8;
  const int sr = tid >> 2, sq2 = tid & 3;

  uint8_t* cbase = coef + (size_t)((b * Hc + h) * NCH + c) * COEF_STRIDE;
  uint16_t* m2out = (uint16_t*)cbase;
  uint16_t* eout = (uint16_t*)(cbase + 8192);
  float* gout = (float*)(cbase + 16384);

  {  // stage K,Q (padded rows of 136 u16)
    const size_t rb = (size_t)(b * Sc + t0 + sr) * DQKc + kh * HDc + sq2 * 32;
#pragma unroll
    for (int u = 0; u < 4; ++u) {
      uint4 kv = *(const uint4*)(Kn + rb + u * 8);
      uint4 qv = *(const uint4*)(Qn + rb + u * 8);
      *(uint4*)&sK[sr * 136 + sq2 * 32 + u * 8] = kv;
      *(uint4*)&sQ[sr * 136 + sq2 * 32 + u * 8] = qv;
    }
  }
  if (tid < 64) {  // log-space decays
    const float* abp = ab + (size_t)(b * Sc + t0 + tid) * 32 + h;
    float av = fmaxf(abp[0], 1e-30f);
    float bv = abp[16];
    float la = log2f(av);
    float L = la;
#pragma unroll
    for (int off = 1; off < 64; off <<= 1) {
      float up = __shfl_up(L, off, 64);
      if (tid >= off) L += up;
    }
    Lb[tid] = L; bbv[tid] = bv;
    gout[tid] = exp2f(L - la);   // gA = G_{i-1}
    gout[64 + tid] = exp2f(L);   // gB = G_i
  }
  __syncthreads();

  // KK = K K^T, QK = Q K^T
  f32x4 kkacc[4] = {}, qkacc[4] = {};
#pragma unroll
  for (int k0 = 0; k0 < 128; k0 += 32) {
    bf16x8 ka = *(const bf16x8*)&sK[(16 * w + lr) * 136 + k0 + lk];
    bf16x8 qa = *(const bf16x8*)&sQ[(16 * w + lr) * 136 + k0 + lk];
#pragma unroll
    for (int n = 0; n < 4; ++n) {
      bf16x8 kb = *(const bf16x8*)&sK[(16 * n + lr) * 136 + k0 + lk];
      kkacc[n] = __builtin_amdgcn_mfma_f32_16x16x32_bf16(ka, kb, kkacc[n], 0, 0, 0);
      qkacc[n] = __builtin_amdgcn_mfma_f32_16x16x32_bf16(qa, kb, qkacc[n], 0, 0, 0);
    }
  }
  __syncthreads();   // sK dead -> Wtf

  const float L63 = Lb[63];
#pragma unroll
  for (int n = 0; n < 4; ++n)
#pragma unroll
    for (int jj = 0; jj < 4; ++jj) {
      const int i = 16 * w + (l >> 4) * 4 + jj;
      const int j = 16 * n + lr;
      float Li = Lb[i];
      float Lim = (i > 0) ? Lb[(i > 0) ? i - 1 : 0] : 0.f;
      float Lj = Lb[j];
      float bj = bbv[j];
      float wv = (j < i) ? exp2f(Lim - Lj) * bj * kkacc[n][jj] : 0.f;
      Wtf[j * 68 + i] = wv;                       // W^T
      float ms = (j <= i) ? exp2f(Li - Lj) * bj * qkacc[n][jj] : 0.f;
      uint16_t mh = f2bf(ms);
      Msh[i * 72 + j] = mh;
      Msl[i * 72 + j] = f2bf(ms - bf2f(mh));
    }
  __syncthreads();

  // Tinv = (I + tril(W,-1))^-1 via forward substitution; wave 0, lane = column j.
  if (tid < 64) {
    float acc[64];
#pragma unroll
    for (int i = 0; i < 64; ++i) acc[i] = 0.f;
#pragma unroll
    for (int ll = 0; ll < 64; ++ll) {
      float xl = ((tid == ll) ? 1.f : 0.f) - acc[ll];
      uint16_t xh = f2bf(xl);
      Thh[tid * 72 + ll] = xh;                    // transposed: [col j][row l]
      Thl[tid * 72 + ll] = f2bf(xl - bf2f(xh));
#pragma unroll
      for (int i = ll + 1; i < 64; ++i)
        acc[i] = fmaf(Wtf[ll * 68 + i], xl, acc[i]);
    }
  }
  __syncthreads();

  // M2 = M_s * Tinv  (3-term hi/lo bf16 MFMA)
  f32x4 m2acc[4] = {};
#pragma unroll
  for (int k0 = 0; k0 < 64; k0 += 32) {
    bf16x8 ah = *(const bf16x8*)&Msh[(16 * w + lr) * 72 + k0 + lk];
    bf16x8 al = *(const bf16x8*)&Msl[(16 * w + lr) * 72 + k0 + lk];
#pragma unroll
    for (int n = 0; n < 4; ++n) {
      bf16x8 bh = *(const bf16x8*)&Thh[(16 * n + lr) * 72 + k0 + lk];
      bf16x8 bl = *(const bf16x8*)&Thl[(16 * n + lr) * 72 + k0 + lk];
      m2acc[n] = __builtin_amdgcn_mfma_f32_16x16x32_bf16(ah, bh, m2acc[n], 0, 0, 0);
      m2acc[n] = __builtin_amdgcn_mfma_f32_16x16x32_bf16(ah, bl, m2acc[n], 0, 0, 0);
      m2acc[n] = __builtin_amdgcn_mfma_f32_16x16x32_bf16(al, bh, m2acc[n], 0, 0, 0);
    }
  }
#pragma unroll
  for (int n = 0; n < 4; ++n)
#pragma unroll
    for (int jj = 0; jj < 4; ++jj) {
      const int i = 16 * w + (l >> 4) * 4 + jj;
      const int j = 16 * n + lr;
      sM2[i * 72 + j] = f2bf(m2acc[n][jj]);
    }
  // E = diag(gC) * Tinv, packed global stores
  {
    const int i2 = tid >> 2, tq = tid & 3;
    float gC = exp2f(L63 - Lb[i2]) * bbv[i2];
    uint32_t pk[8];
#pragma unroll
    for (int p = 0; p < 8; ++p) {
      int t1 = tq * 16 + p * 2;
      float e0 = gC * (bf2f(Thh[(t1 + 0) * 72 + i2]) + bf2f(Thl[(t1 + 0) * 72 + i2]));
      float e1 = gC * (bf2f(Thh[(t1 + 1) * 72 + i2]) + bf2f(Thl[(t1 + 1) * 72 + i2]));
      pk[p] = (uint32_t)f2bf(e0) | ((uint32_t)f2bf(e1) << 16);
    }
    uint4 o0 = make_uint4(pk[0], pk[1], pk[2], pk[3]);
    uint4 o1 = make_uint4(pk[4], pk[5], pk[6], pk[7]);
    *(uint4*)(eout + i2 * 64 + tq * 16) = o0;
    *(uint4*)(eout + i2 * 64 + tq * 16 + 8) = o1;
  }
  __syncthreads();
  {  // packed M2 copy out
    const int i2 = tid >> 2, tq = tid & 3;
    uint4 a0 = *(const uint4*)&sM2[i2 * 72 + tq * 16];
    uint4 a1 = *(const uint4*)&sM2[i2 * 72 + tq * 16 + 8];
    *(uint4*)(m2out + i2 * 64 + tq * 16) = a0;
    *(uint4*)(m2out + i2 * 64 + tq * 16 + 8) = a1;
  }
}

// ---------------- MFMA chunked gated delta-rule scan (T=64) ----------------
// block = (b, h, v-slice of 16). bid mapping puts all consumers of one (b,kh)'s
// K/Q on one XCD (bid&7 == kh). State S (128x16) fp32 in regs + bf16 hi/lo in LDS.
__global__ __launch_bounds__(256) void scan_kernel(const uint16_t* __restrict__ Qn,
                                                   const uint16_t* __restrict__ Kn,
                                                   const uint16_t* __restrict__ C1,
                                                   const uint8_t* __restrict__ coef,
                                                   float* __restrict__ O) {
  __shared__ __align__(16) uint16_t Kb[64 * 136];
  __shared__ __align__(16) uint16_t Qb[64 * 136];
  __shared__ __align__(16) uint16_t Ktb[128 * 72];   // K^T [dk][t]
  __shared__ __align__(16) uint16_t M2b[64 * 72];
  __shared__ __align__(16) uint16_t Eb[64 * 72];
  __shared__ __align__(16) uint16_t Vb[64 * 24];
  __shared__ __align__(16) uint16_t Rt[16 * 72];     // R^T [v][t]
  __shared__ __align__(16) uint16_t D2t[16 * 72];    // D2^T [v][t]
  __shared__ __align__(16) uint16_t Sh[16 * 136];    // S^T hi [v][dk]
  __shared__ __align__(16) uint16_t Slo[16 * 136];   // S^T lo [v][dk]
  __shared__ float gABb[128];                        // gA[64] | gB[64]

  const int bid = blockIdx.x;
  const int kh = bid & 7;
  const int j2 = bid >> 3;
  const int sl = j2 >> 2;
  const int b = (j2 >> 1) & 1;
  const int h = kh * 2 + (j2 & 1);
  const int ch0 = (b * Hc + h) * NCH;

  const int tid = threadIdx.x;
  const int w = tid >> 6, l = tid & 63;
  const int lr = l & 15, lk = (l >> 4) * 8;
  const int row0 = 16 * w + (l >> 4) * 4;
  const int vcol = lr;
  const int sr = tid >> 2, sq2 = tid & 3;

  const size_t kqbase = (size_t)(b * Sc) * DQKc + kh * HDc;
  const size_t vbase = (size_t)(b * Sc) * NCATc + 2048 + h * HDc + sl * 16;
  float* Ob = O + (size_t)(b * Sc) * DVc + h * HDc + sl * 16 + vcol;

  float sreg[2][4] = {};
  uint4 kA[4], kB[4], qA[4], qB[4];

  auto LOADS = [&](int cn, uint4 (&kd)[4], uint4 (&qd)[4], uint4 (&m2d)[2], uint4 (&ed)[2],
                   uint4& vd, float& gd) {
    const size_t rb = kqbase + (size_t)(cn * CT + sr) * DQKc + sq2 * 32;
#pragma unroll
    for (int u = 0; u < 4; ++u) {
      kd[u] = *(const uint4*)(Kn + rb + u * 8);
      qd[u] = *(const uint4*)(Qn + rb + u * 8);
    }
    const uint16_t* cf = (const uint16_t*)(coef + (size_t)(ch0 + cn) * COEF_STRIDE);
#pragma unroll
    for (int e = 0; e < 2; ++e) {
      m2d[e] = *(const uint4*)(cf + sr * 64 + sq2 * 16 + e * 8);
      ed[e] = *(const uint4*)(cf + 4096 + sr * 64 + sq2 * 16 + e * 8);
    }
    if (tid < 128) {
      vd = *(const uint4*)(C1 + vbase + (size_t)(cn * CT + (tid >> 1)) * NCATc + (tid & 1) * 8);
      gd = ((const float*)(cf + 8192))[tid];
    }
  };
  auto WSTAGE = [&](const uint4 (&kd)[4], const uint4 (&qd)[4], const uint4 (&m2d)[2],
                    const uint4 (&ed)[2], const uint4& vd, const float& gd) {
#pragma unroll
    for (int u = 0; u < 4; ++u) {
      *(uint4*)&Kb[sr * 136 + sq2 * 32 + u * 8] = kd[u];
      *(uint4*)&Qb[sr * 136 + sq2 * 32 + u * 8] = qd[u];
    }
#pragma unroll
    for (int e = 0; e < 2; ++e) {
      *(uint4*)&M2b[sr * 72 + sq2 * 16 + e * 8] = m2d[e];
      *(uint4*)&Eb[sr * 72 + sq2 * 16 + e * 8] = ed[e];
    }
    if (tid < 128) {
      *(uint4*)&Vb[(tid >> 1) * 24 + (tid & 1) * 8] = vd;
      gABb[tid] = gd;
    }
  };

  auto CHUNK = [&](int c, bool pre, uint4 (&kcur)[4], uint4 (&knxt)[4],
                   uint4 (&qcur)[4], uint4 (&qnxt)[4]) {
    uint4 m2d[2], ed[2]; uint4 vd; float gd = 0.f;
    if (pre) LOADS(c + 1, knxt, qnxt, m2d, ed, vd, gd);

    // --- Phase A: K^T scatter (chunk c), P = K*S, Pq = Q*S, R = V - gA*P ---
#pragma unroll
    for (int u = 0; u < 4; ++u) {
      const int c0 = sq2 * 32 + u * 8;
      uint32_t x0 = kcur[u].x, x1 = kcur[u].y, x2 = kcur[u].z, x3 = kcur[u].w;
      Ktb[(c0 + 0) * 72 + sr] = (uint16_t)x0; Ktb[(c0 + 1) * 72 + sr] = (uint16_t)(x0 >> 16);
      Ktb[(c0 + 2) * 72 + sr] = (uint16_t)x1; Ktb[(c0 + 3) * 72 + sr] = (uint16_t)(x1 >> 16);
      Ktb[(c0 + 4) * 72 + sr] = (uint16_t)x2; Ktb[(c0 + 5) * 72 + sr] = (uint16_t)(x2 >> 16);
      Ktb[(c0 + 6) * 72 + sr] = (uint16_t)x3; Ktb[(c0 + 7) * 72 + sr] = (uint16_t)(x3 >> 16);
    }
    f32x4 accP = {0, 0, 0, 0}, accPq = {0, 0, 0, 0};
#pragma unroll
    for (int k0 = 0; k0 < 128; k0 += 32) {
      bf16x8 ka = *(const bf16x8*)&Kb[(16 * w + lr) * 136 + k0 + lk];
      bf16x8 qa = *(const bf16x8*)&Qb[(16 * w + lr) * 136 + k0 + lk];
      bf16x8 shf = *(const bf16x8*)&Sh[lr * 136 + k0 + lk];
      bf16x8 slf = *(const bf16x8*)&Slo[lr * 136 + k0 + lk];
      accP = __builtin_amdgcn_mfma_f32_16x16x32_bf16(ka, shf, accP, 0, 0, 0);
      accP = __builtin_amdgcn_mfma_f32_16x16x32_bf16(ka, slf, accP, 0, 0, 0);
      accPq = __builtin_amdgcn_mfma_f32_16x16x32_bf16(qa, shf, accPq, 0, 0, 0);
      accPq = __builtin_amdgcn_mfma_f32_16x16x32_bf16(qa, slf, accPq, 0, 0, 0);
    }
    {
      float rv[4];
#pragma unroll
      for (int j = 0; j < 4; ++j) {
        float vv = bf2f(Vb[(row0 + j) * 24 + vcol]);
        float ga = gABb[row0 + j];
        rv[j] = vv - ga * accP[j];
      }
      uint32_t r01 = (uint32_t)f2bf(rv[0]) | ((uint32_t)f2bf(rv[1]) << 16);
      uint32_t r23 = (uint32_t)f2bf(rv[2]) | ((uint32_t)f2bf(rv[3]) << 16);
      *(uint2*)&Rt[vcol * 72 + row0] = make_uint2(r01, r23);
    }
    __syncthreads();

    // --- Phase B: D2 = E*R, O = gB*Pq + M2*R ---
    f32x4 accD2 = {0, 0, 0, 0}, accO = {0, 0, 0, 0};
#pragma unroll
    for (int k0 = 0; k0 < 64; k0 += 32) {
      bf16x8 rb8 = *(const bf16x8*)&Rt[lr * 72 + k0 + lk];
      bf16x8 ea = *(const bf16x8*)&Eb[(16 * w + lr) * 72 + k0 + lk];
      bf16x8 ma = *(const bf16x8*)&M2b[(16 * w + lr) * 72 + k0 + lk];
      accD2 = __builtin_amdgcn_mfma_f32_16x16x32_bf16(ea, rb8, accD2, 0, 0, 0);
      accO = __builtin_amdgcn_mfma_f32_16x16x32_bf16(ma, rb8, accO, 0, 0, 0);
    }
    {
      float* op = Ob + (size_t)(c * CT) * DVc;
#pragma unroll
      for (int j = 0; j < 4; ++j) {
        float o = gABb[64 + row0 + j] * accPq[j] + accO[j];
        op[(size_t)(row0 + j) * DVc] = o;
      }
      uint32_t d01 = (uint32_t)f2bf(accD2[0]) | ((uint32_t)f2bf(accD2[1]) << 16);
      uint32_t d23 = (uint32_t)f2bf(accD2[2]) | ((uint32_t)f2bf(accD2[3]) << 16);
      *(uint2*)&D2t[vcol * 72 + row0] = make_uint2(d01, d23);
    }
    __syncthreads();

    // --- Phase C: dS = K^T*D2, S = gT*S + dS, stage chunk c+1 ---
    const float gT = gABb[127];
    f32x4 accY[2] = {{0, 0, 0, 0}, {0, 0, 0, 0}};
#pragma unroll
    for (int k0 = 0; k0 < 64; k0 += 32) {
      bf16x8 db = *(const bf16x8*)&D2t[lr * 72 + k0 + lk];
      bf16x8 ka0 = *(const bf16x8*)&Ktb[(32 * w + lr) * 72 + k0 + lk];
      bf16x8 ka1 = *(const bf16x8*)&Ktb[(32 * w + 16 + lr) * 72 + k0 + lk];
      accY[0] = __builtin_amdgcn_mfma_f32_16x16x32_bf16(ka0, db, accY[0], 0, 0, 0);
      accY[1] = __builtin_amdgcn_mfma_f32_16x16x32_bf16(ka1, db, accY[1], 0, 0, 0);
    }
#pragma unroll
    for (int m = 0; m < 2; ++m) {
      uint16_t hi[4], lo[4];
#pragma unroll
      for (int j = 0; j < 4; ++j) {
        float s = gT * sreg[m][j] + accY[m][j];
        sreg[m][j] = s;
        hi[j] = f2bf(s);
        lo[j] = f2bf(s - bf2f(hi[j]));
      }
      const int dk0 = 32 * w + m * 16 + (l >> 4) * 4;
      *(uint2*)&Sh[vcol * 136 + dk0] =
          make_uint2((uint32_t)hi[0] | ((uint32_t)hi[1] << 16),
                     (uint32_t)hi[2] | ((uint32_t)hi[3] << 16));
      *(uint2*)&Slo[vcol * 136 + dk0] =
          make_uint2((uint32_t)lo[0] | ((uint32_t)lo[1] << 16),
                     (uint32_t)lo[2] | ((uint32_t)lo[3] << 16));
    }
    if (pre) WSTAGE(knxt, qnxt, m2d, ed, vd, gd);
    __syncthreads();
  };

  // prologue: stage chunk 0, zero S
  {
    uint4 m2d[2], ed[2]; uint4 vd; float gd = 0.f;
    LOADS(0, kA, qA, m2d, ed, vd, gd);
    WSTAGE(kA, qA, m2d, ed, vd, gd);
  }
  for (int i = tid; i < 16 * 136; i += 256) { Sh[i] = 0; Slo[i] = 0; }
  __syncthreads();

  for (int c2 = 0; c2 < NCH; c2 += 2) {
    CHUNK(c2, true, kA, kB, qA, qB);
    CHUNK(c2 + 1, c2 + 2 < NCH, kB, kA, qB, qA);
  }
}

// ---------------- g = sigmoid(Graw); gOb = bf16(g * O) ----------------
__global__ __launch_bounds__(256) void gmul_kernel(const uint16_t* __restrict__ C1,
                                                   const float* __restrict__ O,
                                                   uint16_t* __restrict__ gOb) {
  int i = blockIdx.x * blockDim.x + threadIdx.x;
  const int n4 = Mc * DVc / 4;
  const int stride = gridDim.x * blockDim.x;
  for (; i < n4; i += stride) {
    int idx = i * 4;
    int row = idx >> 11;
    int col = idx & (DVc - 1);
    ushort4 gr = *(const ushort4*)&C1[(size_t)row * NCATc + 4096 + col];
    float4 ov = *(const float4*)&O[idx];
    ushort4 r;
    r.x = f2bf(sigmoidf_(bf2f(gr.x)) * ov.x);
    r.y = f2bf(sigmoidf_(bf2f(gr.y)) * ov.y);
    r.z = f2bf(sigmoidf_(bf2f(gr.z)) * ov.z);
    r.w = f2bf(sigmoidf_(bf2f(gr.w)) * ov.w);
    *(ushort4*)&gOb[idx] = r;
  }
}

extern "C" void kernel_launch(void* const* d_in, const int* in_sizes, int n_in,
                              void* d_out, int out_size, void* d_ws, size_t ws_size,
                              hipStream_t stream) {
  (void)in_sizes; (void)n_in; (void)out_size; (void)ws_size;
  const float* x     = (const float*)d_in[0];
  const float* wq    = (const float*)d_in[1];
  const float* wk    = (const float*)d_in[2];
  const float* wv    = (const float*)d_in[3];
  const float* wo    = (const float*)d_in[4];
  const float* qcw   = (const float*)d_in[5];
  const float* kcw   = (const float*)d_in[6];
  const float* aw    = (const float*)d_in[7];
  const float* abias = (const float*)d_in[8];
  const float* bw    = (const float*)d_in[9];
  const float* bbias = (const float*)d_in[10];
  const float* gw    = (const float*)d_in[11];
  const float* nqw   = (const float*)d_in[12];
  const float* nkw   = (const float*)d_in[13];

  // workspace layout (bytes), total ~202 MiB
  uint8_t* ws = (uint8_t*)d_ws;
  uint16_t* xb   = (uint16_t*)(ws);                 //  33,554,432  x bf16
  uint16_t* wcat = (uint16_t*)(ws + 33554432);      //  25,165,824  [wq;wk;wv;g_w] bf16
  uint16_t* wob  = (uint16_t*)(ws + 58720256);      //   8,388,608  wo bf16
  uint16_t* c1   = (uint16_t*)(ws + 67108864);      // 100,663,296  x@Wcat^T bf16 (8192x6144)
  float*    abuf = (float*)   (ws + 167772160);     //   1,048,576  alpha|beta
  uint16_t* qn   = (uint16_t*)(ws + 168820736);     //  16,777,216  normed Q bf16
  uint16_t* kn   = (uint16_t*)(ws + 185597952);     //  16,777,216  normed K bf16
  // coef: 2048 chunk-heads x 16896B = 34.6 MB. Overlays xb (dead after GEMM1)
  // and spills ~1 MB into wcat (dead after GEMM1). gOb reuses xb after scan.
  uint8_t*  cofs = (uint8_t*)ws;
  uint16_t* gob  = xb;
  float* obuf = (float*)d_out;                      // d_out doubles as O scratch

  cast_kernel<<<2048, 256, 0, stream>>>(x, xb, Mc * Dc / 4);
  cast_kernel<<<1024, 256, 0, stream>>>(wq, wcat, DQKc * Dc / 4);
  cast_kernel<<<1024, 256, 0, stream>>>(wk, wcat + DQKc * Dc, DQKc * Dc / 4);
  cast_kernel<<<1024, 256, 0, stream>>>(wv, wcat + 2 * DQKc * Dc, DVc * Dc / 4);
  cast_kernel<<<1024, 256, 0, stream>>>(gw, wcat + 2 * DQKc * Dc + DVc * Dc, DVc * Dc / 4);
  cast_kernel<<<1024, 256, 0, stream>>>(wo, wob, DVc * Dc / 4);

  gemm_bt<uint16_t><<<3072, 256, 0, stream>>>(xb, wcat, c1, NCATc, Dc);         // QKVG
  alphabeta_kernel<<<8192, 256, 0, stream>>>(x, aw, abias, bw, bbias, abuf);
  convnorm_kernel<<<16384, 256, 0, stream>>>(c1, qcw, kcw, nqw, nkw, qn, kn);
  scores_kernel<<<2048, 256, 0, stream>>>(qn, kn, abuf, cofs);                  // chunk coefs
  scan_kernel<<<256, 256, 0, stream>>>(qn, kn, c1, cofs, obuf);                 // O -> d_out
  gmul_kernel<<<2048, 256, 0, stream>>>(c1, obuf, gob);                         // gOb -> ws
  gemm_bt<float><<<1024, 256, 0, stream>>>(gob, wob, (float*)d_out, DVc, Dc);   // final
}

// Round 4
// 791.588 us; speedup vs baseline: 2.7088x; 1.1854x over previous
//
#include <hip/hip_runtime.h>
#include <stdint.h>

#define DEV static __device__ __forceinline__

typedef __bf16 bf16x8 __attribute__((ext_vector_type(8)));
typedef float f32x4 __attribute__((ext_vector_type(4)));

constexpr int Bc = 2, Sc = 4096, Dc = 2048, Hc = 16, KVHc = 8, HDc = 128;
constexpr int DQKc = 1024, DVc = 2048;
constexpr int Mc = Bc * Sc;       // 8192 rows
constexpr int NCATc = 6144;       // Q(1024) | K(1024) | V(2048) | Graw(2048)
constexpr int CT = 64;            // scan chunk length
constexpr int NCH = Sc / CT;      // 64 chunks per sequence
constexpr int COEF_STRIDE = 16896; // bytes per chunk-head: M2 8KB | E 8KB | gA 256B | gB 256B
constexpr float EPSc = 1e-6f;

DEV uint16_t f2bf(float f) {
  uint32_t u = __float_as_uint(f);
  u += 0x7FFFu + ((u >> 16) & 1u);   // RNE
  return (uint16_t)(u >> 16);
}
DEV float bf2f(uint16_t h) { return __uint_as_float(((uint32_t)h) << 16); }
DEV float sigmoidf_(float z) { return 1.0f / (1.0f + __expf(-z)); }

DEV void gload16(void* lds, const void* g) {
  auto gp = (const __attribute__((address_space(1))) uint32_t*)(uintptr_t)g;
  auto lp = (__attribute__((address_space(3))) uint32_t*)(uint32_t)(uintptr_t)lds;
  __builtin_amdgcn_global_load_lds(gp, lp, 16, 0, 0);
}

// ---------------- f32 -> bf16 cast ----------------
__global__ __launch_bounds__(256) void cast_kernel(const float* __restrict__ src,
                                                   uint16_t* __restrict__ dst, int n4) {
  int i = blockIdx.x * blockDim.x + threadIdx.x;
  int stride = gridDim.x * blockDim.x;
  for (; i < n4; i += stride) {
    float4 v = *(const float4*)(src + (size_t)i * 4);
    ushort4 o;
    o.x = f2bf(v.x); o.y = f2bf(v.y); o.z = f2bf(v.z); o.w = f2bf(v.w);
    *(ushort4*)(dst + (size_t)i * 4) = o;
  }
}

// ---------------- 256x256 8-phase bf16 GEMM, C = A @ B^T ----------------
// A: (M,K) bf16 row-major; Bw: (N,K) bf16 row-major; C: (M,N) OutT.
// 512 threads = 8 waves (2 M x 4 N), per-wave 128x64 output, BK=64 in two
// 32-wide k-half regions. LDS 128 KiB, double-buffered per K-tile.
// Slot swizzle: 16B-slot s stored at s ^ (row&3) (involution on both sides).
template <typename OutT>
__global__ __launch_bounds__(512, 2) void gemm256_bt(const uint16_t* __restrict__ A,
                                                     const uint16_t* __restrict__ Bw,
                                                     OutT* __restrict__ C, int Ndim, int Kdim) {
  __shared__ uint16_t sT[2][2][2][8192];   // [buf][mat A/B][khalf][256 rows * 32 cols]

  const int nbn = Ndim / 256;
  const int nwg = gridDim.x;
  int q = nwg >> 3, r = nwg & 7;
  int xcd = blockIdx.x & 7, lin = blockIdx.x >> 3;
  int swz = (xcd < r ? xcd * (q + 1) : r * (q + 1) + (xcd - r) * q) + lin;
  const int bm = swz / nbn, bn = swz % nbn;

  const int tid = threadIdx.x;
  const int wid = tid >> 6, lane = tid & 63;
  const int wm = wid >> 2, wn = wid & 3;
  const int lr = lane & 15;
  const int sswz8 = (((lane >> 4) ^ (lr & 3)) * 8);
  const int arow_base = wm * 128 + lr;
  const int brow_base = wn * 64 + lr;

  const uint16_t* Ab = A + (size_t)(bm * 256) * Kdim;
  const uint16_t* Bb = Bw + (size_t)(bn * 256) * Kdim;
  const int NT = Kdim >> 6;

  // staging: thread t issue u covers linear slot L = u*512+t; row=L>>2,
  // physical slot L&3 holds logical slot (L&3)^(row&3).
  int srowA[2], srowB_dummy;
  (void)srowB_dummy;
  int soff[2];
  const int wbase = tid & ~63;
#pragma unroll
  for (int u = 0; u < 2; ++u) {
    int L = u * 512 + tid;
    srowA[u] = L >> 2;
    soff[u] = (((L & 3) ^ ((L >> 2) & 3)) * 8);
  }

  auto STAGE = [&](int buf, int mat, int kh, int kt) {
    const uint16_t* gb = mat == 0 ? Ab : Bb;
    uint16_t* rg = &sT[buf][mat][kh][0];
#pragma unroll
    for (int u = 0; u < 2; ++u) {
      const uint16_t* g = gb + (size_t)srowA[u] * Kdim + kt * 64 + kh * 32 + soff[u];
      gload16(rg + (u * 512 + wbase) * 8, g);
    }
  };

  f32x4 acc[8][4] = {};
  bf16x8 bfr[4];

  // prologue: Kt0 all 4 regions, Kt1 kh0 (A,B)
  STAGE(0, 0, 0, 0); STAGE(0, 1, 0, 0);
  STAGE(0, 0, 1, 0); STAGE(0, 1, 1, 0);
  STAGE(1, 0, 0, 1); STAGE(1, 1, 0, 1);
  asm volatile("s_waitcnt vmcnt(4)" ::: "memory");
  __builtin_amdgcn_s_barrier();

  for (int kt = 0; kt < NT; ++kt) {
    const int buf = kt & 1;
    const uint16_t* aR0 = &sT[buf][0][0][0];
    const uint16_t* bR0 = &sT[buf][1][0][0];
    const uint16_t* aR1 = &sT[buf][0][1][0];
    const uint16_t* bR1 = &sT[buf][1][1][0];

    // ---- P1: k-half 0, m-frags 0..3 (+ all 4 b-frags kh0) ----
    {
      bf16x8 af[4];
#pragma unroll
      for (int m = 0; m < 4; ++m)
        af[m] = *(const bf16x8*)&aR0[(arow_base + m * 16) * 32 + sswz8];
#pragma unroll
      for (int n = 0; n < 4; ++n)
        bfr[n] = *(const bf16x8*)&bR0[(brow_base + n * 16) * 32 + sswz8];
      if (kt + 1 < NT) STAGE(buf ^ 1, 0, 1, kt + 1);
      __builtin_amdgcn_s_setprio(1);
#pragma unroll
      for (int m = 0; m < 4; ++m)
#pragma unroll
        for (int n = 0; n < 4; ++n)
          acc[m][n] = __builtin_amdgcn_mfma_f32_16x16x32_bf16(af[m], bfr[n], acc[m][n], 0, 0, 0);
      __builtin_amdgcn_s_setprio(0);
      __builtin_amdgcn_s_barrier();
    }
    // ---- P2: k-half 0, m-frags 4..7 (b reused) ----
    {
      bf16x8 af[4];
#pragma unroll
      for (int m = 0; m < 4; ++m)
        af[m] = *(const bf16x8*)&aR0[(arow_base + (m + 4) * 16) * 32 + sswz8];
      if (kt + 1 < NT) STAGE(buf ^ 1, 1, 1, kt + 1);
      __builtin_amdgcn_s_setprio(1);
#pragma unroll
      for (int m = 0; m < 4; ++m)
#pragma unroll
        for (int n = 0; n < 4; ++n)
          acc[m + 4][n] = __builtin_amdgcn_mfma_f32_16x16x32_bf16(af[m], bfr[n], acc[m + 4][n], 0, 0, 0);
      __builtin_amdgcn_s_setprio(0);
      __builtin_amdgcn_s_barrier();
    }
    // ---- P3: k-half 1, m-frags 0..3 (+ all 4 b-frags kh1) ----
    {
      bf16x8 af[4];
#pragma unroll
      for (int m = 0; m < 4; ++m)
        af[m] = *(const bf16x8*)&aR1[(arow_base + m * 16) * 32 + sswz8];
#pragma unroll
      for (int n = 0; n < 4; ++n)
        bfr[n] = *(const bf16x8*)&bR1[(brow_base + n * 16) * 32 + sswz8];
      if (kt + 2 < NT) STAGE(buf, 0, 0, kt + 2);
      __builtin_amdgcn_s_setprio(1);
#pragma unroll
      for (int m = 0; m < 4; ++m)
#pragma unroll
        for (int n = 0; n < 4; ++n)
          acc[m][n] = __builtin_amdgcn_mfma_f32_16x16x32_bf16(af[m], bfr[n], acc[m][n], 0, 0, 0);
      __builtin_amdgcn_s_setprio(0);
      __builtin_amdgcn_s_barrier();
    }
    // ---- P4: k-half 1, m-frags 4..7 ----
    {
      bf16x8 af[4];
#pragma unroll
      for (int m = 0; m < 4; ++m)
        af[m] = *(const bf16x8*)&aR1[(arow_base + (m + 4) * 16) * 32 + sswz8];
      if (kt + 2 < NT) STAGE(buf, 1, 0, kt + 2);
      __builtin_amdgcn_s_setprio(1);
#pragma unroll
      for (int m = 0; m < 4; ++m)
#pragma unroll
        for (int n = 0; n < 4; ++n)
          acc[m + 4][n] = __builtin_amdgcn_mfma_f32_16x16x32_bf16(af[m], bfr[n], acc[m + 4][n], 0, 0, 0);
      __builtin_amdgcn_s_setprio(0);
    }
    // ---- K-tile boundary: counted vmcnt, then barrier ----
    if (kt + 1 < NT) {
      if (kt + 2 < NT)
        asm volatile("s_waitcnt vmcnt(4)" ::: "memory");
      else
        asm volatile("s_waitcnt vmcnt(0)" ::: "memory");
      __builtin_amdgcn_s_barrier();
    }
  }

  // epilogue: C write
  const int r0 = (lane >> 4) * 4;
#pragma unroll
  for (int m = 0; m < 8; ++m)
#pragma unroll
    for (int n = 0; n < 4; ++n) {
      int col = bn * 256 + wn * 64 + n * 16 + lr;
#pragma unroll
      for (int j = 0; j < 4; ++j) {
        int row = bm * 256 + wm * 128 + m * 16 + r0 + j;
        float val = acc[m][n][j];
        if constexpr (sizeof(OutT) == 2)
          C[(size_t)row * Ndim + col] = (OutT)f2bf(val);
        else
          C[(size_t)row * Ndim + col] = (OutT)val;
      }
    }
}

// ---------------- alpha/beta (fp32, sigmoid fused) ----------------
__global__ __launch_bounds__(256) void alphabeta_kernel(const float* __restrict__ x,
                                                        const float* __restrict__ aw,
                                                        const float* __restrict__ abias,
                                                        const float* __restrict__ bw,
                                                        const float* __restrict__ bbias,
                                                        float* __restrict__ out) {
  __shared__ float xrow[Dc];
  const int row = blockIdx.x;
  const float* xp = x + (size_t)row * Dc;
  for (int i = threadIdx.x; i < Dc; i += 256) xrow[i] = xp[i];
  __syncthreads();
  const int o = threadIdx.x >> 3, lg = threadIdx.x & 7;
  const float* wrow = (o < 16) ? (aw + (size_t)o * Dc) : (bw + (size_t)(o - 16) * Dc);
  float s = 0.f;
  for (int i = lg * 4; i < Dc; i += 32) {
    float4 xv = *(const float4*)&xrow[i];
    float4 wv = *(const float4*)&wrow[i];
    s += xv.x * wv.x + xv.y * wv.y + xv.z * wv.z + xv.w * wv.w;
  }
  s += __shfl_xor(s, 1); s += __shfl_xor(s, 2); s += __shfl_xor(s, 4);
  if (lg == 0) {
    float bias = (o < 16) ? abias[o] : bbias[o - 16];
    float sig = sigmoidf_(s + bias);
    if (o >= 16) sig *= 0.08838834764831845f;   // 1/sqrt(128)
    out[(size_t)row * 32 + o] = sig;
  }
}

// ---------------- causal depthwise conv (k=4) + head RMSNorm ----------------
__global__ __launch_bounds__(256) void convnorm_kernel(const uint16_t* __restrict__ C1,
                                                       const float* __restrict__ qcw,
                                                       const float* __restrict__ kcw,
                                                       const float* __restrict__ nqw,
                                                       const float* __restrict__ nkw,
                                                       uint16_t* __restrict__ Qn,
                                                       uint16_t* __restrict__ Kn) {
  const int wid = blockIdx.x * 4 + (threadIdx.x >> 6);
  const int lane = threadIdx.x & 63;
  const int kvh = wid & 7;
  const int t = (wid >> 3) & (Sc - 1);
  const int b = wid >> 15;
  float qv[2], kv[2];
#pragma unroll
  for (int half = 0; half < 2; ++half) {
    const int c = lane + half * 64;
    const int ch = kvh * HDc + c;
    float qs = 0.f, ks = 0.f;
#pragma unroll
    for (int j = 0; j < 4; ++j) {
      int tt = t - 3 + j;
      if (tt >= 0) {
        size_t rb = (size_t)(b * Sc + tt) * NCATc;
        qs = fmaf(bf2f(C1[rb + ch]), qcw[ch * 4 + j], qs);
        ks = fmaf(bf2f(C1[rb + 1024 + ch]), kcw[ch * 4 + j], ks);
      }
    }
    qv[half] = qs; kv[half] = ks;
  }
  float sq = qv[0] * qv[0] + qv[1] * qv[1];
  float sk = kv[0] * kv[0] + kv[1] * kv[1];
#pragma unroll
  for (int m = 1; m < 64; m <<= 1) { sq += __shfl_xor(sq, m); sk += __shfl_xor(sk, m); }
  const float rq = rsqrtf(sq * (1.f / HDc) + EPSc);
  const float rk = rsqrtf(sk * (1.f / HDc) + EPSc);
#pragma unroll
  for (int half = 0; half < 2; ++half) {
    const int c = lane + half * 64;
    size_t oidx = (size_t)(b * Sc + t) * DQKc + kvh * HDc + c;
    Qn[oidx] = f2bf(nqw[c] * qv[half] * rq);
    Kn[oidx] = f2bf(nkw[c] * kv[half] * rk);
  }
}

// ---------------- per-chunk coefficient precompute (T=64) ----------------
__global__ __launch_bounds__(256) void scores_kernel(const uint16_t* __restrict__ Qn,
                                                     const uint16_t* __restrict__ Kn,
                                                     const float* __restrict__ ab,
                                                     uint8_t* __restrict__ coef) {
  __shared__ __align__(16) char smem[72192];
  uint16_t* sK = (uint16_t*)smem;                 // [64][136] bf16
  float* Wtf = (float*)smem;                      // [64][68] f32 (alias, after KK/QK)
  uint16_t* sQ = (uint16_t*)(smem + 17408);       // [64][136] bf16
  uint16_t* sM2 = sQ;                             // reuse as [64][72] bf16 later
  uint16_t* Msh = (uint16_t*)(smem + 34816);      // [64][72]
  uint16_t* Msl = (uint16_t*)(smem + 44032);      // [64][72]
  uint16_t* Thh = (uint16_t*)(smem + 53248);      // Tinv^T hi [j][l]
  uint16_t* Thl = (uint16_t*)(smem + 62464);      // Tinv^T lo [j][l]
  float* Lb = (float*)(smem + 71680);             // [64]
  float* bbv = Lb + 64;                           // [64]

  const int bid = blockIdx.x;
  const int c = bid & 63, h = (bid >> 6) & 15, b = bid >> 10;
  const int kh = h >> 1;
  const int t0 = c * 64;
  const int tid = threadIdx.x;
  const int w = tid >> 6, l = tid & 63, lr = l & 15, lk = (l >> 4) * 8;
  const int sr = tid >> 2, sq2 = tid & 3;

  uint8_t* cbase = coef + (size_t)((b * Hc + h) * NCH + c) * COEF_STRIDE;
  uint16_t* m2out = (uint16_t*)cbase;
  uint16_t* eout = (uint16_t*)(cbase + 8192);
  float* gout = (float*)(cbase + 16384);

  {  // stage K,Q (padded rows of 136 u16)
    const size_t rb = (size_t)(b * Sc + t0 + sr) * DQKc + kh * HDc + sq2 * 32;
#pragma unroll
    for (int u = 0; u < 4; ++u) {
      uint4 kv = *(const uint4*)(Kn + rb + u * 8);
      uint4 qv = *(const uint4*)(Qn + rb + u * 8);
      *(uint4*)&sK[sr * 136 + sq2 * 32 + u * 8] = kv;
      *(uint4*)&sQ[sr * 136 + sq2 * 32 + u * 8] = qv;
    }
  }
  if (tid < 64) {  // log-space decays
    const float* abp = ab + (size_t)(b * Sc + t0 + tid) * 32 + h;
    float av = fmaxf(abp[0], 1e-30f);
    float bv = abp[16];
    float la = log2f(av);
    float L = la;
#pragma unroll
    for (int off = 1; off < 64; off <<= 1) {
      float up = __shfl_up(L, off, 64);
      if (tid >= off) L += up;
    }
    Lb[tid] = L; bbv[tid] = bv;
    gout[tid] = exp2f(L - la);   // gA = G_{i-1}
    gout[64 + tid] = exp2f(L);   // gB = G_i
  }
  __syncthreads();

  // KK = K K^T, QK = Q K^T
  f32x4 kkacc[4] = {}, qkacc[4] = {};
#pragma unroll
  for (int k0 = 0; k0 < 128; k0 += 32) {
    bf16x8 ka = *(const bf16x8*)&sK[(16 * w + lr) * 136 + k0 + lk];
    bf16x8 qa = *(const bf16x8*)&sQ[(16 * w + lr) * 136 + k0 + lk];
#pragma unroll
    for (int n = 0; n < 4; ++n) {
      bf16x8 kb = *(const bf16x8*)&sK[(16 * n + lr) * 136 + k0 + lk];
      kkacc[n] = __builtin_amdgcn_mfma_f32_16x16x32_bf16(ka, kb, kkacc[n], 0, 0, 0);
      qkacc[n] = __builtin_amdgcn_mfma_f32_16x16x32_bf16(qa, kb, qkacc[n], 0, 0, 0);
    }
  }
  __syncthreads();   // sK dead -> Wtf

  const float L63 = Lb[63];
#pragma unroll
  for (int n = 0; n < 4; ++n)
#pragma unroll
    for (int jj = 0; jj < 4; ++jj) {
      const int i = 16 * w + (l >> 4) * 4 + jj;
      const int j = 16 * n + lr;
      float Li = Lb[i];
      float Lim = (i > 0) ? Lb[(i > 0) ? i - 1 : 0] : 0.f;
      float Lj = Lb[j];
      float bj = bbv[j];
      float wv = (j < i) ? exp2f(Lim - Lj) * bj * kkacc[n][jj] : 0.f;
      Wtf[j * 68 + i] = wv;                       // W^T
      float ms = (j <= i) ? exp2f(Li - Lj) * bj * qkacc[n][jj] : 0.f;
      uint16_t mh = f2bf(ms);
      Msh[i * 72 + j] = mh;
      Msl[i * 72 + j] = f2bf(ms - bf2f(mh));
    }
  __syncthreads();

  // Tinv = (I + tril(W,-1))^-1 via forward substitution; wave 0, lane = column j.
  if (tid < 64) {
    float acc[64];
#pragma unroll
    for (int i = 0; i < 64; ++i) acc[i] = 0.f;
#pragma unroll
    for (int ll = 0; ll < 64; ++ll) {
      float xl = ((tid == ll) ? 1.f : 0.f) - acc[ll];
      uint16_t xh = f2bf(xl);
      Thh[tid * 72 + ll] = xh;                    // transposed: [col j][row l]
      Thl[tid * 72 + ll] = f2bf(xl - bf2f(xh));
#pragma unroll
      for (int i = ll + 1; i < 64; ++i)
        acc[i] = fmaf(Wtf[ll * 68 + i], xl, acc[i]);
    }
  }
  __syncthreads();

  // M2 = M_s * Tinv  (3-term hi/lo bf16 MFMA)
  f32x4 m2acc[4] = {};
#pragma unroll
  for (int k0 = 0; k0 < 64; k0 += 32) {
    bf16x8 ah = *(const bf16x8*)&Msh[(16 * w + lr) * 72 + k0 + lk];
    bf16x8 al = *(const bf16x8*)&Msl[(16 * w + lr) * 72 + k0 + lk];
#pragma unroll
    for (int n = 0; n < 4; ++n) {
      bf16x8 bh = *(const bf16x8*)&Thh[(16 * n + lr) * 72 + k0 + lk];
      bf16x8 bl = *(const bf16x8*)&Thl[(16 * n + lr) * 72 + k0 + lk];
      m2acc[n] = __builtin_amdgcn_mfma_f32_16x16x32_bf16(ah, bh, m2acc[n], 0, 0, 0);
      m2acc[n] = __builtin_amdgcn_mfma_f32_16x16x32_bf16(ah, bl, m2acc[n], 0, 0, 0);
      m2acc[n] = __builtin_amdgcn_mfma_f32_16x16x32_bf16(al, bh, m2acc[n], 0, 0, 0);
    }
  }
#pragma unroll
  for (int n = 0; n < 4; ++n)
#pragma unroll
    for (int jj = 0; jj < 4; ++jj) {
      const int i = 16 * w + (l >> 4) * 4 + jj;
      const int j = 16 * n + lr;
      sM2[i * 72 + j] = f2bf(m2acc[n][jj]);
    }
  // E = diag(gC) * Tinv, packed global stores
  {
    const int i2 = tid >> 2, tq = tid & 3;
    float gC = exp2f(L63 - Lb[i2]) * bbv[i2];
    uint32_t pk[8];
#pragma unroll
    for (int p = 0; p < 8; ++p) {
      int t1 = tq * 16 + p * 2;
      float e0 = gC * (bf2f(Thh[(t1 + 0) * 72 + i2]) + bf2f(Thl[(t1 + 0) * 72 + i2]));
      float e1 = gC * (bf2f(Thh[(t1 + 1) * 72 + i2]) + bf2f(Thl[(t1 + 1) * 72 + i2]));
      pk[p] = (uint32_t)f2bf(e0) | ((uint32_t)f2bf(e1) << 16);
    }
    uint4 o0 = make_uint4(pk[0], pk[1], pk[2], pk[3]);
    uint4 o1 = make_uint4(pk[4], pk[5], pk[6], pk[7]);
    *(uint4*)(eout + i2 * 64 + tq * 16) = o0;
    *(uint4*)(eout + i2 * 64 + tq * 16 + 8) = o1;
  }
  __syncthreads();
  {  // packed M2 copy out
    const int i2 = tid >> 2, tq = tid & 3;
    uint4 a0 = *(const uint4*)&sM2[i2 * 72 + tq * 16];
    uint4 a1 = *(const uint4*)&sM2[i2 * 72 + tq * 16 + 8];
    *(uint4*)(m2out + i2 * 64 + tq * 16) = a0;
    *(uint4*)(m2out + i2 * 64 + tq * 16 + 8) = a1;
  }
}

// ---------------- MFMA chunked gated delta-rule scan (T=64) ----------------
__global__ __launch_bounds__(256) void scan_kernel(const uint16_t* __restrict__ Qn,
                                                   const uint16_t* __restrict__ Kn,
                                                   const uint16_t* __restrict__ C1,
                                                   const uint8_t* __restrict__ coef,
                                                   float* __restrict__ O) {
  __shared__ __align__(16) uint16_t Kb[64 * 136];
  __shared__ __align__(16) uint16_t Qb[64 * 136];
  __shared__ __align__(16) uint16_t Ktb[128 * 72];   // K^T [dk][t]
  __shared__ __align__(16) uint16_t M2b[64 * 72];
  __shared__ __align__(16) uint16_t Eb[64 * 72];
  __shared__ __align__(16) uint16_t Vb[64 * 24];
  __shared__ __align__(16) uint16_t Rt[16 * 72];     // R^T [v][t]
  __shared__ __align__(16) uint16_t D2t[16 * 72];    // D2^T [v][t]
  __shared__ __align__(16) uint16_t Sh[16 * 136];    // S^T hi [v][dk]
  __shared__ __align__(16) uint16_t Slo[16 * 136];   // S^T lo [v][dk]
  __shared__ float gABb[128];                        // gA[64] | gB[64]

  const int bid = blockIdx.x;
  const int kh = bid & 7;
  const int j2 = bid >> 3;
  const int sl = j2 >> 2;
  const int b = (j2 >> 1) & 1;
  const int h = kh * 2 + (j2 & 1);
  const int ch0 = (b * Hc + h) * NCH;

  const int tid = threadIdx.x;
  const int w = tid >> 6, l = tid & 63;
  const int lr = l & 15, lk = (l >> 4) * 8;
  const int row0 = 16 * w + (l >> 4) * 4;
  const int vcol = lr;
  const int sr = tid >> 2, sq2 = tid & 3;

  const size_t kqbase = (size_t)(b * Sc) * DQKc + kh * HDc;
  const size_t vbase = (size_t)(b * Sc) * NCATc + 2048 + h * HDc + sl * 16;
  float* Ob = O + (size_t)(b * Sc) * DVc + h * HDc + sl * 16 + vcol;

  float sreg[2][4] = {};
  uint4 kA[4], kB[4], qA[4], qB[4];

  auto LOADS = [&](int cn, uint4 (&kd)[4], uint4 (&qd)[4], uint4 (&m2d)[2], uint4 (&ed)[2],
                   uint4& vd, float& gd) {
    const size_t rb = kqbase + (size_t)(cn * CT + sr) * DQKc + sq2 * 32;
#pragma unroll
    for (int u = 0; u < 4; ++u) {
      kd[u] = *(const uint4*)(Kn + rb + u * 8);
      qd[u] = *(const uint4*)(Qn + rb + u * 8);
    }
    const uint16_t* cf = (const uint16_t*)(coef + (size_t)(ch0 + cn) * COEF_STRIDE);
#pragma unroll
    for (int e = 0; e < 2; ++e) {
      m2d[e] = *(const uint4*)(cf + sr * 64 + sq2 * 16 + e * 8);
      ed[e] = *(const uint4*)(cf + 4096 + sr * 64 + sq2 * 16 + e * 8);
    }
    if (tid < 128) {
      vd = *(const uint4*)(C1 + vbase + (size_t)(cn * CT + (tid >> 1)) * NCATc + (tid & 1) * 8);
      gd = ((const float*)(cf + 8192))[tid];
    }
  };
  auto WSTAGE = [&](const uint4 (&kd)[4], const uint4 (&qd)[4], const uint4 (&m2d)[2],
                    const uint4 (&ed)[2], const uint4& vd, const float& gd) {
#pragma unroll
    for (int u = 0; u < 4; ++u) {
      *(uint4*)&Kb[sr * 136 + sq2 * 32 + u * 8] = kd[u];
      *(uint4*)&Qb[sr * 136 + sq2 * 32 + u * 8] = qd[u];
    }
#pragma unroll
    for (int e = 0; e < 2; ++e) {
      *(uint4*)&M2b[sr * 72 + sq2 * 16 + e * 8] = m2d[e];
      *(uint4*)&Eb[sr * 72 + sq2 * 16 + e * 8] = ed[e];
    }
    if (tid < 128) {
      *(uint4*)&Vb[(tid >> 1) * 24 + (tid & 1) * 8] = vd;
      gABb[tid] = gd;
    }
  };

  auto CHUNK = [&](int c, bool pre, uint4 (&kcur)[4], uint4 (&knxt)[4],
                   uint4 (&qcur)[4], uint4 (&qnxt)[4]) {
    uint4 m2d[2], ed[2]; uint4 vd; float gd = 0.f;
    if (pre) LOADS(c + 1, knxt, qnxt, m2d, ed, vd, gd);

    // --- Phase A: K^T scatter (chunk c), P = K*S, Pq = Q*S, R = V - gA*P ---
#pragma unroll
    for (int u = 0; u < 4; ++u) {
      const int c0 = sq2 * 32 + u * 8;
      uint32_t x0 = kcur[u].x, x1 = kcur[u].y, x2 = kcur[u].z, x3 = kcur[u].w;
      Ktb[(c0 + 0) * 72 + sr] = (uint16_t)x0; Ktb[(c0 + 1) * 72 + sr] = (uint16_t)(x0 >> 16);
      Ktb[(c0 + 2) * 72 + sr] = (uint16_t)x1; Ktb[(c0 + 3) * 72 + sr] = (uint16_t)(x1 >> 16);
      Ktb[(c0 + 4) * 72 + sr] = (uint16_t)x2; Ktb[(c0 + 5) * 72 + sr] = (uint16_t)(x2 >> 16);
      Ktb[(c0 + 6) * 72 + sr] = (uint16_t)x3; Ktb[(c0 + 7) * 72 + sr] = (uint16_t)(x3 >> 16);
    }
    f32x4 accP = {0, 0, 0, 0}, accPq = {0, 0, 0, 0};
#pragma unroll
    for (int k0 = 0; k0 < 128; k0 += 32) {
      bf16x8 ka = *(const bf16x8*)&Kb[(16 * w + lr) * 136 + k0 + lk];
      bf16x8 qa = *(const bf16x8*)&Qb[(16 * w + lr) * 136 + k0 + lk];
      bf16x8 shf = *(const bf16x8*)&Sh[lr * 136 + k0 + lk];
      bf16x8 slf = *(const bf16x8*)&Slo[lr * 136 + k0 + lk];
      accP = __builtin_amdgcn_mfma_f32_16x16x32_bf16(ka, shf, accP, 0, 0, 0);
      accP = __builtin_amdgcn_mfma_f32_16x16x32_bf16(ka, slf, accP, 0, 0, 0);
      accPq = __builtin_amdgcn_mfma_f32_16x16x32_bf16(qa, shf, accPq, 0, 0, 0);
      accPq = __builtin_amdgcn_mfma_f32_16x16x32_bf16(qa, slf, accPq, 0, 0, 0);
    }
    {
      float rv[4];
#pragma unroll
      for (int j = 0; j < 4; ++j) {
        float vv = bf2f(Vb[(row0 + j) * 24 + vcol]);
        float ga = gABb[row0 + j];
        rv[j] = vv - ga * accP[j];
      }
      uint32_t r01 = (uint32_t)f2bf(rv[0]) | ((uint32_t)f2bf(rv[1]) << 16);
      uint32_t r23 = (uint32_t)f2bf(rv[2]) | ((uint32_t)f2bf(rv[3]) << 16);
      *(uint2*)&Rt[vcol * 72 + row0] = make_uint2(r01, r23);
    }
    __syncthreads();

    // --- Phase B: D2 = E*R, O = gB*Pq + M2*R ---
    f32x4 accD2 = {0, 0, 0, 0}, accO = {0, 0, 0, 0};
#pragma unroll
    for (int k0 = 0; k0 < 64; k0 += 32) {
      bf16x8 rb8 = *(const bf16x8*)&Rt[lr * 72 + k0 + lk];
      bf16x8 ea = *(const bf16x8*)&Eb[(16 * w + lr) * 72 + k0 + lk];
      bf16x8 ma = *(const bf16x8*)&M2b[(16 * w + lr) * 72 + k0 + lk];
      accD2 = __builtin_amdgcn_mfma_f32_16x16x32_bf16(ea, rb8, accD2, 0, 0, 0);
      accO = __builtin_amdgcn_mfma_f32_16x16x32_bf16(ma, rb8, accO, 0, 0, 0);
    }
    {
      float* op = Ob + (size_t)(c * CT) * DVc;
#pragma unroll
      for (int j = 0; j < 4; ++j) {
        float o = gABb[64 + row0 + j] * accPq[j] + accO[j];
        op[(size_t)(row0 + j) * DVc] = o;
      }
      uint32_t d01 = (uint32_t)f2bf(accD2[0]) | ((uint32_t)f2bf(accD2[1]) << 16);
      uint32_t d23 = (uint32_t)f2bf(accD2[2]) | ((uint32_t)f2bf(accD2[3]) << 16);
      *(uint2*)&D2t[vcol * 72 + row0] = make_uint2(d01, d23);
    }
    __syncthreads();

    // --- Phase C: dS = K^T*D2, S = gT*S + dS, stage chunk c+1 ---
    const float gT = gABb[127];
    f32x4 accY[2] = {{0, 0, 0, 0}, {0, 0, 0, 0}};
#pragma unroll
    for (int k0 = 0; k0 < 64; k0 += 32) {
      bf16x8 db = *(const bf16x8*)&D2t[lr * 72 + k0 + lk];
      bf16x8 ka0 = *(const bf16x8*)&Ktb[(32 * w + lr) * 72 + k0 + lk];
      bf16x8 ka1 = *(const bf16x8*)&Ktb[(32 * w + 16 + lr) * 72 + k0 + lk];
      accY[0] = __builtin_amdgcn_mfma_f32_16x16x32_bf16(ka0, db, accY[0], 0, 0, 0);
      accY[1] = __builtin_amdgcn_mfma_f32_16x16x32_bf16(ka1, db, accY[1], 0, 0, 0);
    }
#pragma unroll
    for (int m = 0; m < 2; ++m) {
      uint16_t hi[4], lo[4];
#pragma unroll
      for (int j = 0; j < 4; ++j) {
        float s = gT * sreg[m][j] + accY[m][j];
        sreg[m][j] = s;
        hi[j] = f2bf(s);
        lo[j] = f2bf(s - bf2f(hi[j]));
      }
      const int dk0 = 32 * w + m * 16 + (l >> 4) * 4;
      *(uint2*)&Sh[vcol * 136 + dk0] =
          make_uint2((uint32_t)hi[0] | ((uint32_t)hi[1] << 16),
                     (uint32_t)hi[2] | ((uint32_t)hi[3] << 16));
      *(uint2*)&Slo[vcol * 136 + dk0] =
          make_uint2((uint32_t)lo[0] | ((uint32_t)lo[1] << 16),
                     (uint32_t)lo[2] | ((uint32_t)lo[3] << 16));
    }
    if (pre) WSTAGE(knxt, qnxt, m2d, ed, vd, gd);
    __syncthreads();
  };

  // prologue: stage chunk 0, zero S
  {
    uint4 m2d[2], ed[2]; uint4 vd; float gd = 0.f;
    LOADS(0, kA, qA, m2d, ed, vd, gd);
    WSTAGE(kA, qA, m2d, ed, vd, gd);
  }
  for (int i = tid; i < 16 * 136; i += 256) { Sh[i] = 0; Slo[i] = 0; }
  __syncthreads();

  for (int c2 = 0; c2 < NCH; c2 += 2) {
    CHUNK(c2, true, kA, kB, qA, qB);
    CHUNK(c2 + 1, c2 + 2 < NCH, kB, kA, qB, qA);
  }
}

// ---------------- g = sigmoid(Graw); gOb = bf16(g * O) ----------------
__global__ __launch_bounds__(256) void gmul_kernel(const uint16_t* __restrict__ C1,
                                                   const float* __restrict__ O,
                                                   uint16_t* __restrict__ gOb) {
  int i = blockIdx.x * blockDim.x + threadIdx.x;
  const int n4 = Mc * DVc / 4;
  const int stride = gridDim.x * blockDim.x;
  for (; i < n4; i += stride) {
    int idx = i * 4;
    int row = idx >> 11;
    int col = idx & (DVc - 1);
    ushort4 gr = *(const ushort4*)&C1[(size_t)row * NCATc + 4096 + col];
    float4 ov = *(const float4*)&O[idx];
    ushort4 r;
    r.x = f2bf(sigmoidf_(bf2f(gr.x)) * ov.x);
    r.y = f2bf(sigmoidf_(bf2f(gr.y)) * ov.y);
    r.z = f2bf(sigmoidf_(bf2f(gr.z)) * ov.z);
    r.w = f2bf(sigmoidf_(bf2f(gr.w)) * ov.w);
    *(ushort4*)&gOb[idx] = r;
  }
}

extern "C" void kernel_launch(void* const* d_in, const int* in_sizes, int n_in,
                              void* d_out, int out_size, void* d_ws, size_t ws_size,
                              hipStream_t stream) {
  (void)in_sizes; (void)n_in; (void)out_size; (void)ws_size;
  const float* x     = (const float*)d_in[0];
  const float* wq    = (const float*)d_in[1];
  const float* wk    = (const float*)d_in[2];
  const float* wv    = (const float*)d_in[3];
  const float* wo    = (const float*)d_in[4];
  const float* qcw   = (const float*)d_in[5];
  const float* kcw   = (const float*)d_in[6];
  const float* aw    = (const float*)d_in[7];
  const float* abias = (const float*)d_in[8];
  const float* bw    = (const float*)d_in[9];
  const float* bbias = (const float*)d_in[10];
  const float* gw    = (const float*)d_in[11];
  const float* nqw   = (const float*)d_in[12];
  const float* nkw   = (const float*)d_in[13];

  // workspace layout (bytes), total ~202 MiB
  uint8_t* ws = (uint8_t*)d_ws;
  uint16_t* xb   = (uint16_t*)(ws);                 //  33,554,432  x bf16
  uint16_t* wcat = (uint16_t*)(ws + 33554432);      //  25,165,824  [wq;wk;wv;g_w] bf16
  uint16_t* wob  = (uint16_t*)(ws + 58720256);      //   8,388,608  wo bf16
  uint16_t* c1   = (uint16_t*)(ws + 67108864);      // 100,663,296  x@Wcat^T bf16 (8192x6144)
  float*    abuf = (float*)   (ws + 167772160);     //   1,048,576  alpha|beta
  uint16_t* qn   = (uint16_t*)(ws + 168820736);     //  16,777,216  normed Q bf16
  uint16_t* kn   = (uint16_t*)(ws + 185597952);     //  16,777,216  normed K bf16
  uint8_t*  cofs = (uint8_t*)ws;                    // coef overlays xb+wcat (dead after GEMM1)
  uint16_t* gob  = xb;                              // reuse again after scan
  float* obuf = (float*)d_out;                      // d_out doubles as O scratch

  cast_kernel<<<2048, 256, 0, stream>>>(x, xb, Mc * Dc / 4);
  cast_kernel<<<1024, 256, 0, stream>>>(wq, wcat, DQKc * Dc / 4);
  cast_kernel<<<1024, 256, 0, stream>>>(wk, wcat + DQKc * Dc, DQKc * Dc / 4);
  cast_kernel<<<1024, 256, 0, stream>>>(wv, wcat + 2 * DQKc * Dc, DVc * Dc / 4);
  cast_kernel<<<1024, 256, 0, stream>>>(gw, wcat + 2 * DQKc * Dc + DVc * Dc, DVc * Dc / 4);
  cast_kernel<<<1024, 256, 0, stream>>>(wo, wob, DVc * Dc / 4);

  gemm256_bt<uint16_t><<<768, 512, 0, stream>>>(xb, wcat, c1, NCATc, Dc);       // QKVG
  alphabeta_kernel<<<8192, 256, 0, stream>>>(x, aw, abias, bw, bbias, abuf);
  convnorm_kernel<<<16384, 256, 0, stream>>>(c1, qcw, kcw, nqw, nkw, qn, kn);
  scores_kernel<<<2048, 256, 0, stream>>>(qn, kn, abuf, cofs);                  // chunk coefs
  scan_kernel<<<256, 256, 0, stream>>>(qn, kn, c1, cofs, obuf);                 // O -> d_out
  gmul_kernel<<<2048, 256, 0, stream>>>(c1, obuf, gob);                         // gOb -> ws
  gemm256_bt<float><<<256, 512, 0, stream>>>(gob, wob, (float*)d_out, DVc, Dc); // final
}